// Round 3
// baseline (1721.492 us; speedup 1.0000x reference)
//
#include <hip/hip_runtime.h>
#include <math.h>

#define NN 100000
#define NM ((size_t)NN * 128)

// ============================================================================
// prep_weights: build effective weight matrices (all tiny)
//  B_item [128][384]: cols 0-127 = Wk[0]; 128-255 = Wv[0];
//                     256-383 = Wq[0] @ BD(A2)^T, scaled by rel_pri[2]/sqrt(dk)
//  B_user [128][512]: Wk[1] | Wv[1] | Wq[1]@BD(A0)^T*pri0 | Wq[1]@BD(A1)^T*pri1
//  Wfin[0] = BD(M2)@Wa[0]; Wfin[1] = 0.5*BD(M0)@Wa[1]; Wfin[2] = 0.5*BD(M1)@Wa[1]
// ============================================================================
__global__ void prep_weights(
    const float* __restrict__ Wk, const float* __restrict__ bk,
    const float* __restrict__ Wq, const float* __restrict__ bq,
    const float* __restrict__ Wv, const float* __restrict__ bv,
    const float* __restrict__ Wa, const float* __restrict__ rel_pri,
    const float* __restrict__ rel_att, const float* __restrict__ rel_msg,
    float* __restrict__ B_item, float* __restrict__ bias_item,
    float* __restrict__ B_user, float* __restrict__ bias_user,
    float* __restrict__ Wfin)
{
    int t = blockIdx.x * 256 + threadIdx.x;

    if (t < 128 * 384) {                       // B_item
        int k = t / 384, c = t % 384;
        float v;
        if (c < 128)      v = Wk[k * 128 + c];
        else if (c < 256) v = Wv[k * 128 + (c - 128)];
        else {
            int cc = c - 256, h = cc >> 4, d = cc & 15;
            const float* A = rel_att + 2 * 2048 + h * 256 + d * 16;  // A2[h][d][:]
            const float* w = Wq + k * 128 + h * 16;
            float s = 0.f;
            #pragma unroll
            for (int e = 0; e < 16; ++e) s += w[e] * A[e];
            v = s * (rel_pri[16 + h] * 0.25f);
        }
        B_item[k * 384 + c] = v;
        return;
    }
    t -= 128 * 384;
    if (t < 384) {                             // bias_item
        int c = t; float v;
        if (c < 128)      v = bk[c];
        else if (c < 256) v = bv[c - 128];
        else {
            int cc = c - 256, h = cc >> 4, d = cc & 15;
            const float* A = rel_att + 2 * 2048 + h * 256 + d * 16;
            const float* b = bq + h * 16;
            float s = 0.f;
            #pragma unroll
            for (int e = 0; e < 16; ++e) s += b[e] * A[e];
            v = s * (rel_pri[16 + h] * 0.25f);
        }
        bias_item[c] = v;
        return;
    }
    t -= 384;
    if (t < 128 * 512) {                       // B_user
        int k = t / 512, c = t % 512;
        float v;
        if (c < 128)      v = Wk[16384 + k * 128 + c];
        else if (c < 256) v = Wv[16384 + k * 128 + (c - 128)];
        else {
            int rr = (c < 384) ? 0 : 1;
            int cc = (c - 256) & 127, h = cc >> 4, d = cc & 15;
            const float* A = rel_att + rr * 2048 + h * 256 + d * 16;
            const float* w = Wq + 16384 + k * 128 + h * 16;
            float s = 0.f;
            #pragma unroll
            for (int e = 0; e < 16; ++e) s += w[e] * A[e];
            v = s * (rel_pri[rr * 8 + h] * 0.25f);
        }
        B_user[k * 512 + c] = v;
        return;
    }
    t -= 128 * 512;
    if (t < 512) {                             // bias_user
        int c = t; float v;
        if (c < 128)      v = bk[128 + c];
        else if (c < 256) v = bv[128 + c - 128];
        else {
            int rr = (c < 384) ? 0 : 1;
            int cc = (c - 256) & 127, h = cc >> 4, d = cc & 15;
            const float* A = rel_att + rr * 2048 + h * 256 + d * 16;
            const float* b = bq + 128 + h * 16;
            float s = 0.f;
            #pragma unroll
            for (int e = 0; e < 16; ++e) s += b[e] * A[e];
            v = s * (rel_pri[rr * 8 + h] * 0.25f);
        }
        bias_user[c] = v;
        return;
    }
    t -= 512;
    if (t < 3 * 16384) {                       // Wfin
        int which = t / 16384, rem = t % 16384;
        int rin = rem / 128, c = rem % 128;
        int h = rin >> 4, d = rin & 15;
        const float* M; const float* W; float scale;
        if (which == 0)      { M = rel_msg + 2 * 2048 + h * 256 + d * 16; W = Wa;         scale = 1.0f; }
        else if (which == 1) { M = rel_msg + 0        + h * 256 + d * 16; W = Wa + 16384; scale = 0.5f; }
        else                 { M = rel_msg + 2048     + h * 256 + d * 16; W = Wa + 16384; scale = 0.5f; }
        float s = 0.f;
        #pragma unroll
        for (int e = 0; e < 16; ++e) s += M[e] * W[(h * 16 + e) * 128 + c];
        Wfin[which * 16384 + rin * 128 + c] = s * scale;
    }
}

// ============================================================================
// gemm_node: out[gy] = A[M x 128] @ B[:, gy*128 : +128] + bias[gy*128..]
// Per-K-step LDS staging (16 KB total). __launch_bounds__(256,4): cap at
// 128 VGPR so occupancy is 4 blocks/CU (LDS allows 10). 8x8 per thread.
// Thread columns: tx*4..+3 and 64+tx*4..+3 (contiguous b128 spans, 2-way max).
// ============================================================================
struct OutPtrs { float* p[4]; };

__global__ __launch_bounds__(256, 4) void gemm_node(
    const float* __restrict__ A, const float* __restrict__ B,
    const float* __restrict__ bias, OutPtrs outs, int M, int Bstride)
{
    __shared__ float Bs[16 * 128];
    __shared__ float As[128 * 16];
    const int tid = threadIdx.x;
    const int gy = blockIdx.y;
    const int tile = blockIdx.x;
    const int tx = tid & 15, ty = tid >> 4;

    float acc[8][8];
    #pragma unroll
    for (int i = 0; i < 8; ++i)
        #pragma unroll
        for (int j = 0; j < 8; ++j) acc[i][j] = 0.f;

    for (int ks = 0; ks < 128; ks += 16) {
        __syncthreads();
        #pragma unroll
        for (int it = 0; it < 2; ++it) {
            int f = tid + it * 256;            // 512 float4 over Bs[16][128]
            int k = f >> 5, lc4 = f & 31;
            *(float4*)(Bs + k * 128 + lc4 * 4) =
                *(const float4*)(B + (size_t)(ks + k) * Bstride + gy * 128 + lc4 * 4);
        }
        #pragma unroll
        for (int it = 0; it < 2; ++it) {
            int f = tid + it * 256;            // 512 float4 over As[128][16]
            int row = f >> 2, kk4 = f & 3;
            int r = tile * 128 + row;
            float4 v = make_float4(0.f, 0.f, 0.f, 0.f);
            if (r < M) v = *(const float4*)(A + (size_t)r * 128 + ks + kk4 * 4);
            *(float4*)(As + row * 16 + kk4 * 4) = v;
        }
        __syncthreads();
        #pragma unroll
        for (int kk = 0; kk < 16; ++kk) {
            float4 b0 = *(const float4*)(Bs + kk * 128 + tx * 4);
            float4 b1 = *(const float4*)(Bs + kk * 128 + 64 + tx * 4);
            #pragma unroll
            for (int i = 0; i < 8; ++i) {
                float a = As[(ty + 16 * i) * 16 + kk];
                acc[i][0] += a * b0.x; acc[i][1] += a * b0.y;
                acc[i][2] += a * b0.z; acc[i][3] += a * b0.w;
                acc[i][4] += a * b1.x; acc[i][5] += a * b1.y;
                acc[i][6] += a * b1.z; acc[i][7] += a * b1.w;
            }
        }
    }

    float4 bi0 = *(const float4*)(bias + gy * 128 + tx * 4);
    float4 bi1 = *(const float4*)(bias + gy * 128 + 64 + tx * 4);
    float* out = outs.p[gy];
    #pragma unroll
    for (int i = 0; i < 8; ++i) {
        int r = tile * 128 + ty + 16 * i;
        if (r < M) {
            float4 o0 = make_float4(acc[i][0] + bi0.x, acc[i][1] + bi0.y,
                                    acc[i][2] + bi0.z, acc[i][3] + bi0.w);
            float4 o1 = make_float4(acc[i][4] + bi1.x, acc[i][5] + bi1.y,
                                    acc[i][6] + bi1.z, acc[i][7] + bi1.w);
            *(float4*)(out + (size_t)r * 128 + tx * 4) = o0;
            *(float4*)(out + (size_t)r * 128 + 64 + tx * 4) = o1;
        }
    }
}

// ============================================================================
// gemm_final: out = (A0@B0 [+ A1@B1] + ba) * alpha + hin * (1-alpha)
// A0/A1 may alias out: each block reads only the rows it writes, and all
// reads complete (syncthreads-structured K loop) before the epilogue stores.
// ============================================================================
__global__ __launch_bounds__(256, 4) void gemm_final(
    const float* A0, const float* A1,
    const float* __restrict__ B0, const float* B1,
    const float* __restrict__ ba, const float* __restrict__ skipv, int nid,
    const float* __restrict__ hin, float* out, int M)
{
    __shared__ float Bs[16 * 128];
    __shared__ float As[128 * 16];
    const int tid = threadIdx.x;
    const int tile = blockIdx.x;
    const int tx = tid & 15, ty = tid >> 4;

    float acc[8][8];
    #pragma unroll
    for (int i = 0; i < 8; ++i)
        #pragma unroll
        for (int j = 0; j < 8; ++j) acc[i][j] = 0.f;

    const float* Ap[2] = { A0, A1 };
    const float* Bp[2] = { B0, B1 };
    const int nA = (A1 != nullptr) ? 2 : 1;

    for (int p = 0; p < nA; ++p) {
        const float* Acur = Ap[p];
        const float* Bcur = Bp[p];
        for (int ks = 0; ks < 128; ks += 16) {
            __syncthreads();
            #pragma unroll
            for (int it = 0; it < 2; ++it) {
                int f = tid + it * 256;
                int k = f >> 5, lc4 = f & 31;
                *(float4*)(Bs + k * 128 + lc4 * 4) =
                    *(const float4*)(Bcur + (size_t)(ks + k) * 128 + lc4 * 4);
            }
            #pragma unroll
            for (int it = 0; it < 2; ++it) {
                int f = tid + it * 256;
                int row = f >> 2, kk4 = f & 3;
                int r = tile * 128 + row;
                float4 v = make_float4(0.f, 0.f, 0.f, 0.f);
                if (r < M) v = *(const float4*)(Acur + (size_t)r * 128 + ks + kk4 * 4);
                *(float4*)(As + row * 16 + kk4 * 4) = v;
            }
            __syncthreads();
            #pragma unroll
            for (int kk = 0; kk < 16; ++kk) {
                float4 b0 = *(const float4*)(Bs + kk * 128 + tx * 4);
                float4 b1 = *(const float4*)(Bs + kk * 128 + 64 + tx * 4);
                #pragma unroll
                for (int i = 0; i < 8; ++i) {
                    float a = As[(ty + 16 * i) * 16 + kk];
                    acc[i][0] += a * b0.x; acc[i][1] += a * b0.y;
                    acc[i][2] += a * b0.z; acc[i][3] += a * b0.w;
                    acc[i][4] += a * b1.x; acc[i][5] += a * b1.y;
                    acc[i][6] += a * b1.z; acc[i][7] += a * b1.w;
                }
            }
        }
    }

    float sv = skipv[nid];
    float alpha = 1.f / (1.f + __expf(-sv));
    float beta = 1.f - alpha;
    float4 ba0 = *(const float4*)(ba + tx * 4);
    float4 ba1 = *(const float4*)(ba + 64 + tx * 4);
    #pragma unroll
    for (int i = 0; i < 8; ++i) {
        int r = tile * 128 + ty + 16 * i;
        if (r < M) {
            float4 h0 = *(const float4*)(hin + (size_t)r * 128 + tx * 4);
            float4 h1 = *(const float4*)(hin + (size_t)r * 128 + 64 + tx * 4);
            float4 o0 = make_float4((acc[i][0] + ba0.x) * alpha + h0.x * beta,
                                    (acc[i][1] + ba0.y) * alpha + h0.y * beta,
                                    (acc[i][2] + ba0.z) * alpha + h0.z * beta,
                                    (acc[i][3] + ba0.w) * alpha + h0.w * beta);
            float4 o1 = make_float4((acc[i][4] + ba1.x) * alpha + h1.x * beta,
                                    (acc[i][5] + ba1.y) * alpha + h1.y * beta,
                                    (acc[i][6] + ba1.z) * alpha + h1.z * beta,
                                    (acc[i][7] + ba1.w) * alpha + h1.w * beta);
            *(float4*)(out + (size_t)r * 128 + tx * 4) = o0;
            *(float4*)(out + (size_t)r * 128 + 64 + tx * 4) = o1;
        }
    }
}

// ============================================================================
// CSR build — fused across the 3 etypes. cnt/pos/offs are [3][NN]; scan is a
// single global exclusive scan over all 3*NN counts, so offs indexes directly
// into the single 1M-entry csrc buffer.
// ============================================================================
__global__ void zero_int(int* __restrict__ p, int n) {
    int i = blockIdx.x * 256 + threadIdx.x;
    if (i < n) p[i] = 0;
}
__global__ void hist3(const int* __restrict__ d0, const int* __restrict__ d1,
                      const int* __restrict__ d2, int E0, int E1, int E2,
                      int* __restrict__ cnt) {
    int e = blockIdx.x * 256 + threadIdx.x;
    int g;
    if (e < E0) g = 0 * NN + d0[e];
    else if (e < E0 + E1) g = 1 * NN + d1[e - E0];
    else if (e < E0 + E1 + E2) g = 2 * NN + d2[e - E0 - E1];
    else return;
    atomicAdd(&cnt[g], 1);
}
__global__ void scan1(const int* __restrict__ cnt, int* __restrict__ offs,
                      int* __restrict__ psum, int n) {
    __shared__ int sm[1024];
    int t = threadIdx.x, i = blockIdx.x * 1024 + t;
    int v = (i < n) ? cnt[i] : 0;
    sm[t] = v; __syncthreads();
    for (int off = 1; off < 1024; off <<= 1) {
        int x = (t >= off) ? sm[t - off] : 0;
        __syncthreads();
        sm[t] += x;
        __syncthreads();
    }
    if (i < n) offs[i] = sm[t] - v;           // exclusive
    if (t == 1023) psum[blockIdx.x] = sm[1023];
}
__global__ void scan2(int* __restrict__ psum, int nb) {
    __shared__ int sm[512];
    int t = threadIdx.x;
    int v = (t < nb) ? psum[t] : 0;
    sm[t] = v; __syncthreads();
    for (int off = 1; off < 512; off <<= 1) {
        int x = (t >= off) ? sm[t - off] : 0;
        __syncthreads();
        sm[t] += x;
        __syncthreads();
    }
    if (t < nb) psum[t] = sm[t] - v;
}
__global__ void scan3(int* __restrict__ offs, const int* __restrict__ psum, int n) {
    int i = blockIdx.x * 256 + threadIdx.x;
    if (i < n) offs[i] += psum[i >> 10];
}
__global__ void scatter3(const int* __restrict__ s0, const int* __restrict__ d0,
                         const int* __restrict__ s1, const int* __restrict__ d1,
                         const int* __restrict__ s2, const int* __restrict__ d2,
                         int E0, int E1, int E2,
                         const int* __restrict__ offs, int* __restrict__ pos,
                         int* __restrict__ csrc) {
    int e = blockIdx.x * 256 + threadIdx.x;
    int g, s;
    if (e < E0) { g = 0 * NN + d0[e]; s = s0[e]; }
    else if (e < E0 + E1) { int l = e - E0; g = 1 * NN + d1[l]; s = s1[l]; }
    else if (e < E0 + E1 + E2) { int l = e - E0 - E1; g = 2 * NN + d2[l]; s = s2[l]; }
    else return;
    int p = atomicAdd(&pos[g], 1);
    csrc[offs[g] + p] = s;
}

// ============================================================================
// edge_attn: one 8-lane group per dst node, lane = head. Online softmax.
// rel_pri/sqrt(dk) pre-folded into qt. aggout may alias qt (row g is fully
// read into registers before being overwritten at the end; no group reads
// any other group's row).
// ============================================================================
__global__ __launch_bounds__(256) void edge_attn(
    const float* qt, const float* __restrict__ kb, const float* __restrict__ vb,
    const int* __restrict__ offs, const int* __restrict__ deg,
    const int* __restrict__ csrc, float* aggout)
{
    int g = blockIdx.x * 32 + (threadIdx.x >> 3);
    int h = threadIdx.x & 7;
    if (g >= NN) return;

    const float* qrow = qt + (size_t)g * 128 + h * 16;
    float4 q0 = *(const float4*)(qrow);
    float4 q1 = *(const float4*)(qrow + 4);
    float4 q2 = *(const float4*)(qrow + 8);
    float4 q3 = *(const float4*)(qrow + 12);

    int s = offs[g], dg = deg[g];
    float m = -__builtin_inff(), sum = 0.f;
    float4 a0 = make_float4(0, 0, 0, 0), a1 = a0, a2 = a0, a3 = a0;

    for (int e = 0; e < dg; ++e) {
        int src = csrc[s + e];
        const float* krow = kb + (size_t)src * 128 + h * 16;
        float4 k0 = *(const float4*)(krow);
        float4 k1 = *(const float4*)(krow + 4);
        float4 k2 = *(const float4*)(krow + 8);
        float4 k3 = *(const float4*)(krow + 12);
        float sc = q0.x * k0.x + q0.y * k0.y + q0.z * k0.z + q0.w * k0.w
                 + q1.x * k1.x + q1.y * k1.y + q1.z * k1.z + q1.w * k1.w
                 + q2.x * k2.x + q2.y * k2.y + q2.z * k2.z + q2.w * k2.w
                 + q3.x * k3.x + q3.y * k3.y + q3.z * k3.z + q3.w * k3.w;
        float mn = fmaxf(m, sc);
        float cr = __expf(m - mn);            // 0 on first edge (m = -inf)
        float w = __expf(sc - mn);
        sum = sum * cr + w;
        m = mn;
        const float* vrow = vb + (size_t)src * 128 + h * 16;
        float4 v0 = *(const float4*)(vrow);
        float4 v1 = *(const float4*)(vrow + 4);
        float4 v2 = *(const float4*)(vrow + 8);
        float4 v3 = *(const float4*)(vrow + 12);
        a0.x = a0.x * cr + w * v0.x; a0.y = a0.y * cr + w * v0.y;
        a0.z = a0.z * cr + w * v0.z; a0.w = a0.w * cr + w * v0.w;
        a1.x = a1.x * cr + w * v1.x; a1.y = a1.y * cr + w * v1.y;
        a1.z = a1.z * cr + w * v1.z; a1.w = a1.w * cr + w * v1.w;
        a2.x = a2.x * cr + w * v2.x; a2.y = a2.y * cr + w * v2.y;
        a2.z = a2.z * cr + w * v2.z; a2.w = a2.w * cr + w * v2.w;
        a3.x = a3.x * cr + w * v3.x; a3.y = a3.y * cr + w * v3.y;
        a3.z = a3.z * cr + w * v3.z; a3.w = a3.w * cr + w * v3.w;
    }

    float inv = (dg > 0) ? 1.f / sum : 0.f;
    float* orow = aggout + (size_t)g * 128 + h * 16;
    a0.x *= inv; a0.y *= inv; a0.z *= inv; a0.w *= inv;
    a1.x *= inv; a1.y *= inv; a1.z *= inv; a1.w *= inv;
    a2.x *= inv; a2.y *= inv; a2.z *= inv; a2.w *= inv;
    a3.x *= inv; a3.y *= inv; a3.z *= inv; a3.w *= inv;
    *(float4*)(orow) = a0;
    *(float4*)(orow + 4) = a1;
    *(float4*)(orow + 8) = a2;
    *(float4*)(orow + 12) = a3;
}

// ============================================================================
extern "C" void kernel_launch(void* const* d_in, const int* in_sizes, int n_in,
                              void* d_out, int out_size, void* d_ws, size_t ws_size,
                              hipStream_t stream)
{
    const float* h_item = (const float*)d_in[0];
    const float* h_user = (const float*)d_in[1];
    const float* Wk  = (const float*)d_in[2];
    const float* bk  = (const float*)d_in[3];
    const float* Wq  = (const float*)d_in[4];
    const float* bq  = (const float*)d_in[5];
    const float* Wv  = (const float*)d_in[6];
    const float* bv  = (const float*)d_in[7];
    const float* Wa  = (const float*)d_in[8];
    const float* ba  = (const float*)d_in[9];
    const float* rel_pri = (const float*)d_in[10];
    const float* rel_att = (const float*)d_in[11];
    const float* rel_msg = (const float*)d_in[12];
    const float* skipv   = (const float*)d_in[13];
    const int* s0 = (const int*)d_in[14]; const int* d0 = (const int*)d_in[15];
    const int* s1 = (const int*)d_in[16]; const int* d1 = (const int*)d_in[17];
    const int* s2 = (const int*)d_in[18]; const int* d2 = (const int*)d_in[19];
    const int E0 = in_sizes[14], E1 = in_sizes[16], E2 = in_sizes[18];
    const int Etot = E0 + E1 + E2;

    // ws layout (floats): 5 node matrices + small weights + CSR ints (~262 MB).
    // qt0 aliases out_user, qt2 aliases out_item (d_out is scratch until the
    // final GEMMs, which are read-before-write safe per block).
    float* ws = (float*)d_ws;
    float* kb_i = ws;
    float* vb_i = ws + NM;
    float* kb_u = ws + 2 * NM;
    float* vb_u = ws + 3 * NM;
    float* qt1  = ws + 4 * NM;
    float* wreg = ws + 5 * NM;
    float* B_item    = wreg;                   // 49152
    float* bias_item = wreg + 49152;           // 384
    float* B_user    = wreg + 49536;           // 65536
    float* bias_user = wreg + 115072;          // 512
    float* Wfin      = wreg + 115584;          // 3*16384 = 49152
    int* ibuf = (int*)(wreg + 115584 + 49152);
    int* cnt  = ibuf;                          // 3*NN
    int* pos  = ibuf + 3 * NN;                 // 3*NN
    int* offs = ibuf + 6 * NN;                 // 3*NN
    int* psum = ibuf + 9 * NN;                 // 512
    int* csrc = ibuf + 9 * NN + 512;           // Etot (1,000,000)

    float* out_item = (float*)d_out;           // doubles as qt2 / agg2
    float* out_user = (float*)d_out + NM;      // doubles as qt0 / agg0

    prep_weights<<<644, 256, 0, stream>>>(Wk, bk, Wq, bq, Wv, bv, Wa, rel_pri,
                                          rel_att, rel_msg,
                                          B_item, bias_item, B_user, bias_user, Wfin);

    const int tiles = (NN + 127) / 128;        // 782
    OutPtrs oi; oi.p[0] = kb_i; oi.p[1] = vb_i; oi.p[2] = out_item; oi.p[3] = nullptr;
    OutPtrs ou; ou.p[0] = kb_u; ou.p[1] = vb_u; ou.p[2] = out_user; ou.p[3] = qt1;
    gemm_node<<<dim3(tiles, 3), 256, 0, stream>>>(h_item, B_item, bias_item, oi, NN, 384);
    gemm_node<<<dim3(tiles, 4), 256, 0, stream>>>(h_user, B_user, bias_user, ou, NN, 512);

    // CSR build (fused over etypes)
    zero_int<<<(6 * NN + 255) / 256, 256, 0, stream>>>(ibuf, 6 * NN);  // cnt+pos
    hist3<<<(Etot + 255) / 256, 256, 0, stream>>>(d0, d1, d2, E0, E1, E2, cnt);
    const int nscan = 3 * NN;
    const int nb1024 = (nscan + 1023) / 1024;  // 293
    scan1<<<nb1024, 1024, 0, stream>>>(cnt, offs, psum, nscan);
    scan2<<<1, 512, 0, stream>>>(psum, nb1024);
    scan3<<<(nscan + 255) / 256, 256, 0, stream>>>(offs, psum, nscan);
    scatter3<<<(Etot + 255) / 256, 256, 0, stream>>>(s0, d0, s1, d1, s2, d2,
                                                     E0, E1, E2, offs, pos, csrc);

    // attention + aggregation per etype (agg aliases qt)
    const int gblocks = (NN + 31) / 32;        // 3125
    edge_attn<<<gblocks, 256, 0, stream>>>(out_user, kb_i, vb_i,
                                           offs,          cnt,          csrc, out_user);
    edge_attn<<<gblocks, 256, 0, stream>>>(qt1,      kb_i, vb_i,
                                           offs + NN,     cnt + NN,     csrc, qt1);
    edge_attn<<<gblocks, 256, 0, stream>>>(out_item, kb_u, vb_u,
                                           offs + 2 * NN, cnt + 2 * NN, csrc, out_item);

    gemm_final<<<tiles, 256, 0, stream>>>(out_item, nullptr, Wfin, nullptr,
                                          ba, skipv, 0, h_item, out_item, NN);
    gemm_final<<<tiles, 256, 0, stream>>>(out_user, qt1, Wfin + 16384, Wfin + 2 * 16384,
                                          ba + 128, skipv, 1, h_user, out_user, NN);
}

// Round 5
// 1022.766 us; speedup vs baseline: 1.6832x; 1.6832x over previous
//
#include <hip/hip_runtime.h>
#include <math.h>

#define NN 100000
#define NM ((size_t)NN * 128)

// ============================================================================
// prep_weights: build effective weight matrices (all tiny)
//  B_item [128][384]: cols 0-127 = Wk[0]; 128-255 = Wv[0];
//                     256-383 = Wq[0] @ BD(A2)^T, scaled by rel_pri[2]/sqrt(dk)
//  B_user [128][512]: Wk[1] | Wv[1] | Wq[1]@BD(A0)^T*pri0 | Wq[1]@BD(A1)^T*pri1
//  Wfin[0] = BD(M2)@Wa[0]; Wfin[1] = 0.5*BD(M0)@Wa[1]; Wfin[2] = 0.5*BD(M1)@Wa[1]
// ============================================================================
__global__ void prep_weights(
    const float* __restrict__ Wk, const float* __restrict__ bk,
    const float* __restrict__ Wq, const float* __restrict__ bq,
    const float* __restrict__ Wv, const float* __restrict__ bv,
    const float* __restrict__ Wa, const float* __restrict__ rel_pri,
    const float* __restrict__ rel_att, const float* __restrict__ rel_msg,
    float* __restrict__ B_item, float* __restrict__ bias_item,
    float* __restrict__ B_user, float* __restrict__ bias_user,
    float* __restrict__ Wfin)
{
    int t = blockIdx.x * 256 + threadIdx.x;

    if (t < 128 * 384) {                       // B_item
        int k = t / 384, c = t % 384;
        float v;
        if (c < 128)      v = Wk[k * 128 + c];
        else if (c < 256) v = Wv[k * 128 + (c - 128)];
        else {
            int cc = c - 256, h = cc >> 4, d = cc & 15;
            const float* A = rel_att + 2 * 2048 + h * 256 + d * 16;  // A2[h][d][:]
            const float* w = Wq + k * 128 + h * 16;
            float s = 0.f;
            #pragma unroll
            for (int e = 0; e < 16; ++e) s += w[e] * A[e];
            v = s * (rel_pri[16 + h] * 0.25f);
        }
        B_item[k * 384 + c] = v;
        return;
    }
    t -= 128 * 384;
    if (t < 384) {                             // bias_item
        int c = t; float v;
        if (c < 128)      v = bk[c];
        else if (c < 256) v = bv[c - 128];
        else {
            int cc = c - 256, h = cc >> 4, d = cc & 15;
            const float* A = rel_att + 2 * 2048 + h * 256 + d * 16;
            const float* b = bq + h * 16;
            float s = 0.f;
            #pragma unroll
            for (int e = 0; e < 16; ++e) s += b[e] * A[e];
            v = s * (rel_pri[16 + h] * 0.25f);
        }
        bias_item[c] = v;
        return;
    }
    t -= 384;
    if (t < 128 * 512) {                       // B_user
        int k = t / 512, c = t % 512;
        float v;
        if (c < 128)      v = Wk[16384 + k * 128 + c];
        else if (c < 256) v = Wv[16384 + k * 128 + (c - 128)];
        else {
            int rr = (c < 384) ? 0 : 1;
            int cc = (c - 256) & 127, h = cc >> 4, d = cc & 15;
            const float* A = rel_att + rr * 2048 + h * 256 + d * 16;
            const float* w = Wq + 16384 + k * 128 + h * 16;
            float s = 0.f;
            #pragma unroll
            for (int e = 0; e < 16; ++e) s += w[e] * A[e];
            v = s * (rel_pri[rr * 8 + h] * 0.25f);
        }
        B_user[k * 512 + c] = v;
        return;
    }
    t -= 128 * 512;
    if (t < 512) {                             // bias_user
        int c = t; float v;
        if (c < 128)      v = bk[128 + c];
        else if (c < 256) v = bv[128 + c - 128];
        else {
            int rr = (c < 384) ? 0 : 1;
            int cc = (c - 256) & 127, h = cc >> 4, d = cc & 15;
            const float* A = rel_att + rr * 2048 + h * 256 + d * 16;
            const float* b = bq + 128 + h * 16;
            float s = 0.f;
            #pragma unroll
            for (int e = 0; e < 16; ++e) s += b[e] * A[e];
            v = s * (rel_pri[rr * 8 + h] * 0.25f);
        }
        bias_user[c] = v;
        return;
    }
    t -= 512;
    if (t < 3 * 16384) {                       // Wfin
        int which = t / 16384, rem = t % 16384;
        int rin = rem / 128, c = rem % 128;
        int h = rin >> 4, d = rin & 15;
        const float* M; const float* W; float scale;
        if (which == 0)      { M = rel_msg + 2 * 2048 + h * 256 + d * 16; W = Wa;         scale = 1.0f; }
        else if (which == 1) { M = rel_msg + 0        + h * 256 + d * 16; W = Wa + 16384; scale = 0.5f; }
        else                 { M = rel_msg + 2048     + h * 256 + d * 16; W = Wa + 16384; scale = 0.5f; }
        float s = 0.f;
        #pragma unroll
        for (int e = 0; e < 16; ++e) s += M[e] * W[(h * 16 + e) * 128 + c];
        Wfin[which * 16384 + rin * 128 + c] = s * scale;
    }
}

// ============================================================================
// gemm_node: out[gy] = A[M x 128] @ B[:, gy*128 : +128] + bias[gy*128..]
// Per-K-step LDS staging (16 KB total). 8x8 per thread.
// NOTE: __launch_bounds__(256) ONLY — round-3 bench proved (256,4) capped the
// allocator at 64 VGPR and spilled the 64-entry acc array (WRITE_SIZE 23x
// output, VALUBusy 9.5%, 506us). Let the allocator take ~128 VGPR, no spills.
// ============================================================================
struct OutPtrs { float* p[4]; };

__global__ __launch_bounds__(256) void gemm_node(
    const float* __restrict__ A, const float* __restrict__ B,
    const float* __restrict__ bias, OutPtrs outs, int M, int Bstride)
{
    __shared__ float Bs[16 * 128];
    __shared__ float As[128 * 16];
    const int tid = threadIdx.x;
    const int gy = blockIdx.y;
    const int tile = blockIdx.x;
    const int tx = tid & 15, ty = tid >> 4;

    float acc[8][8];
    #pragma unroll
    for (int i = 0; i < 8; ++i)
        #pragma unroll
        for (int j = 0; j < 8; ++j) acc[i][j] = 0.f;

    for (int ks = 0; ks < 128; ks += 16) {
        __syncthreads();
        #pragma unroll
        for (int it = 0; it < 2; ++it) {
            int f = tid + it * 256;            // 512 float4 over Bs[16][128]
            int k = f >> 5, lc4 = f & 31;
            *(float4*)(Bs + k * 128 + lc4 * 4) =
                *(const float4*)(B + (size_t)(ks + k) * Bstride + gy * 128 + lc4 * 4);
        }
        #pragma unroll
        for (int it = 0; it < 2; ++it) {
            int f = tid + it * 256;            // 512 float4 over As[128][16]
            int row = f >> 2, kk4 = f & 3;
            int r = tile * 128 + row;
            float4 v = make_float4(0.f, 0.f, 0.f, 0.f);
            if (r < M) v = *(const float4*)(A + (size_t)r * 128 + ks + kk4 * 4);
            *(float4*)(As + row * 16 + kk4 * 4) = v;
        }
        __syncthreads();
        #pragma unroll
        for (int kk = 0; kk < 16; ++kk) {
            float4 b0 = *(const float4*)(Bs + kk * 128 + tx * 4);
            float4 b1 = *(const float4*)(Bs + kk * 128 + 64 + tx * 4);
            #pragma unroll
            for (int i = 0; i < 8; ++i) {
                float a = As[(ty + 16 * i) * 16 + kk];
                acc[i][0] += a * b0.x; acc[i][1] += a * b0.y;
                acc[i][2] += a * b0.z; acc[i][3] += a * b0.w;
                acc[i][4] += a * b1.x; acc[i][5] += a * b1.y;
                acc[i][6] += a * b1.z; acc[i][7] += a * b1.w;
            }
        }
    }

    float4 bi0 = *(const float4*)(bias + gy * 128 + tx * 4);
    float4 bi1 = *(const float4*)(bias + gy * 128 + 64 + tx * 4);
    float* out = outs.p[gy];
    #pragma unroll
    for (int i = 0; i < 8; ++i) {
        int r = tile * 128 + ty + 16 * i;
        if (r < M) {
            float4 o0 = make_float4(acc[i][0] + bi0.x, acc[i][1] + bi0.y,
                                    acc[i][2] + bi0.z, acc[i][3] + bi0.w);
            float4 o1 = make_float4(acc[i][4] + bi1.x, acc[i][5] + bi1.y,
                                    acc[i][6] + bi1.z, acc[i][7] + bi1.w);
            *(float4*)(out + (size_t)r * 128 + tx * 4) = o0;
            *(float4*)(out + (size_t)r * 128 + 64 + tx * 4) = o1;
        }
    }
}

// ============================================================================
// gemm_final: out = (A0@B0 [+ A1@B1] + ba) * alpha + hin * (1-alpha)
// A0/A1 may alias out: each block reads only the rows it writes, and all
// reads complete (syncthreads-structured K loop) before the epilogue stores.
// __launch_bounds__(256) only — see gemm_node note (spill regression fix).
// ============================================================================
__global__ __launch_bounds__(256) void gemm_final(
    const float* A0, const float* A1,
    const float* __restrict__ B0, const float* B1,
    const float* __restrict__ ba, const float* __restrict__ skipv, int nid,
    const float* __restrict__ hin, float* out, int M)
{
    __shared__ float Bs[16 * 128];
    __shared__ float As[128 * 16];
    const int tid = threadIdx.x;
    const int tile = blockIdx.x;
    const int tx = tid & 15, ty = tid >> 4;

    float acc[8][8];
    #pragma unroll
    for (int i = 0; i < 8; ++i)
        #pragma unroll
        for (int j = 0; j < 8; ++j) acc[i][j] = 0.f;

    const float* Ap[2] = { A0, A1 };
    const float* Bp[2] = { B0, B1 };
    const int nA = (A1 != nullptr) ? 2 : 1;

    for (int p = 0; p < nA; ++p) {
        const float* Acur = Ap[p];
        const float* Bcur = Bp[p];
        for (int ks = 0; ks < 128; ks += 16) {
            __syncthreads();
            #pragma unroll
            for (int it = 0; it < 2; ++it) {
                int f = tid + it * 256;
                int k = f >> 5, lc4 = f & 31;
                *(float4*)(Bs + k * 128 + lc4 * 4) =
                    *(const float4*)(Bcur + (size_t)(ks + k) * 128 + lc4 * 4);
            }
            #pragma unroll
            for (int it = 0; it < 2; ++it) {
                int f = tid + it * 256;
                int row = f >> 2, kk4 = f & 3;
                int r = tile * 128 + row;
                float4 v = make_float4(0.f, 0.f, 0.f, 0.f);
                if (r < M) v = *(const float4*)(Acur + (size_t)r * 128 + ks + kk4 * 4);
                *(float4*)(As + row * 16 + kk4 * 4) = v;
            }
            __syncthreads();
            #pragma unroll
            for (int kk = 0; kk < 16; ++kk) {
                float4 b0 = *(const float4*)(Bs + kk * 128 + tx * 4);
                float4 b1 = *(const float4*)(Bs + kk * 128 + 64 + tx * 4);
                #pragma unroll
                for (int i = 0; i < 8; ++i) {
                    float a = As[(ty + 16 * i) * 16 + kk];
                    acc[i][0] += a * b0.x; acc[i][1] += a * b0.y;
                    acc[i][2] += a * b0.z; acc[i][3] += a * b0.w;
                    acc[i][4] += a * b1.x; acc[i][5] += a * b1.y;
                    acc[i][6] += a * b1.z; acc[i][7] += a * b1.w;
                }
            }
        }
    }

    float sv = skipv[nid];
    float alpha = 1.f / (1.f + __expf(-sv));
    float beta = 1.f - alpha;
    float4 ba0 = *(const float4*)(ba + tx * 4);
    float4 ba1 = *(const float4*)(ba + 64 + tx * 4);
    #pragma unroll
    for (int i = 0; i < 8; ++i) {
        int r = tile * 128 + ty + 16 * i;
        if (r < M) {
            float4 h0 = *(const float4*)(hin + (size_t)r * 128 + tx * 4);
            float4 h1 = *(const float4*)(hin + (size_t)r * 128 + 64 + tx * 4);
            float4 o0 = make_float4((acc[i][0] + ba0.x) * alpha + h0.x * beta,
                                    (acc[i][1] + ba0.y) * alpha + h0.y * beta,
                                    (acc[i][2] + ba0.z) * alpha + h0.z * beta,
                                    (acc[i][3] + ba0.w) * alpha + h0.w * beta);
            float4 o1 = make_float4((acc[i][4] + ba1.x) * alpha + h1.x * beta,
                                    (acc[i][5] + ba1.y) * alpha + h1.y * beta,
                                    (acc[i][6] + ba1.z) * alpha + h1.z * beta,
                                    (acc[i][7] + ba1.w) * alpha + h1.w * beta);
            *(float4*)(out + (size_t)r * 128 + tx * 4) = o0;
            *(float4*)(out + (size_t)r * 128 + 64 + tx * 4) = o1;
        }
    }
}

// ============================================================================
// CSR build — fused across the 3 etypes. cnt/pos/offs are [3][NN]; scan is a
// single global exclusive scan over all 3*NN counts, so offs indexes directly
// into the single 1M-entry csrc buffer.
// ============================================================================
__global__ void zero_int(int* __restrict__ p, int n) {
    int i = blockIdx.x * 256 + threadIdx.x;
    if (i < n) p[i] = 0;
}
__global__ void hist3(const int* __restrict__ d0, const int* __restrict__ d1,
                      const int* __restrict__ d2, int E0, int E1, int E2,
                      int* __restrict__ cnt) {
    int e = blockIdx.x * 256 + threadIdx.x;
    int g;
    if (e < E0) g = 0 * NN + d0[e];
    else if (e < E0 + E1) g = 1 * NN + d1[e - E0];
    else if (e < E0 + E1 + E2) g = 2 * NN + d2[e - E0 - E1];
    else return;
    atomicAdd(&cnt[g], 1);
}
__global__ void scan1(const int* __restrict__ cnt, int* __restrict__ offs,
                      int* __restrict__ psum, int n) {
    __shared__ int sm[1024];
    int t = threadIdx.x, i = blockIdx.x * 1024 + t;
    int v = (i < n) ? cnt[i] : 0;
    sm[t] = v; __syncthreads();
    for (int off = 1; off < 1024; off <<= 1) {
        int x = (t >= off) ? sm[t - off] : 0;
        __syncthreads();
        sm[t] += x;
        __syncthreads();
    }
    if (i < n) offs[i] = sm[t] - v;           // exclusive
    if (t == 1023) psum[blockIdx.x] = sm[1023];
}
__global__ void scan2(int* __restrict__ psum, int nb) {
    __shared__ int sm[512];
    int t = threadIdx.x;
    int v = (t < nb) ? psum[t] : 0;
    sm[t] = v; __syncthreads();
    for (int off = 1; off < 512; off <<= 1) {
        int x = (t >= off) ? sm[t - off] : 0;
        __syncthreads();
        sm[t] += x;
        __syncthreads();
    }
    if (t < nb) psum[t] = sm[t] - v;
}
__global__ void scan3(int* __restrict__ offs, const int* __restrict__ psum, int n) {
    int i = blockIdx.x * 256 + threadIdx.x;
    if (i < n) offs[i] += psum[i >> 10];
}
__global__ void scatter3(const int* __restrict__ s0, const int* __restrict__ d0,
                         const int* __restrict__ s1, const int* __restrict__ d1,
                         const int* __restrict__ s2, const int* __restrict__ d2,
                         int E0, int E1, int E2,
                         const int* __restrict__ offs, int* __restrict__ pos,
                         int* __restrict__ csrc) {
    int e = blockIdx.x * 256 + threadIdx.x;
    int g, s;
    if (e < E0) { g = 0 * NN + d0[e]; s = s0[e]; }
    else if (e < E0 + E1) { int l = e - E0; g = 1 * NN + d1[l]; s = s1[l]; }
    else if (e < E0 + E1 + E2) { int l = e - E0 - E1; g = 2 * NN + d2[l]; s = s2[l]; }
    else return;
    int p = atomicAdd(&pos[g], 1);
    csrc[offs[g] + p] = s;
}

// ============================================================================
// edge_attn: one 8-lane group per dst node, lane = head. Online softmax.
// rel_pri/sqrt(dk) pre-folded into qt. aggout may alias qt (row g is fully
// read into registers before being overwritten at the end; no group reads
// any other group's row).
// ============================================================================
__global__ __launch_bounds__(256) void edge_attn(
    const float* qt, const float* __restrict__ kb, const float* __restrict__ vb,
    const int* __restrict__ offs, const int* __restrict__ deg,
    const int* __restrict__ csrc, float* aggout)
{
    int g = blockIdx.x * 32 + (threadIdx.x >> 3);
    int h = threadIdx.x & 7;
    if (g >= NN) return;

    const float* qrow = qt + (size_t)g * 128 + h * 16;
    float4 q0 = *(const float4*)(qrow);
    float4 q1 = *(const float4*)(qrow + 4);
    float4 q2 = *(const float4*)(qrow + 8);
    float4 q3 = *(const float4*)(qrow + 12);

    int s = offs[g], dg = deg[g];
    float m = -__builtin_inff(), sum = 0.f;
    float4 a0 = make_float4(0, 0, 0, 0), a1 = a0, a2 = a0, a3 = a0;

    for (int e = 0; e < dg; ++e) {
        int src = csrc[s + e];
        const float* krow = kb + (size_t)src * 128 + h * 16;
        float4 k0 = *(const float4*)(krow);
        float4 k1 = *(const float4*)(krow + 4);
        float4 k2 = *(const float4*)(krow + 8);
        float4 k3 = *(const float4*)(krow + 12);
        float sc = q0.x * k0.x + q0.y * k0.y + q0.z * k0.z + q0.w * k0.w
                 + q1.x * k1.x + q1.y * k1.y + q1.z * k1.z + q1.w * k1.w
                 + q2.x * k2.x + q2.y * k2.y + q2.z * k2.z + q2.w * k2.w
                 + q3.x * k3.x + q3.y * k3.y + q3.z * k3.z + q3.w * k3.w;
        float mn = fmaxf(m, sc);
        float cr = __expf(m - mn);            // 0 on first edge (m = -inf)
        float w = __expf(sc - mn);
        sum = sum * cr + w;
        m = mn;
        const float* vrow = vb + (size_t)src * 128 + h * 16;
        float4 v0 = *(const float4*)(vrow);
        float4 v1 = *(const float4*)(vrow + 4);
        float4 v2 = *(const float4*)(vrow + 8);
        float4 v3 = *(const float4*)(vrow + 12);
        a0.x = a0.x * cr + w * v0.x; a0.y = a0.y * cr + w * v0.y;
        a0.z = a0.z * cr + w * v0.z; a0.w = a0.w * cr + w * v0.w;
        a1.x = a1.x * cr + w * v1.x; a1.y = a1.y * cr + w * v1.y;
        a1.z = a1.z * cr + w * v1.z; a1.w = a1.w * cr + w * v1.w;
        a2.x = a2.x * cr + w * v2.x; a2.y = a2.y * cr + w * v2.y;
        a2.z = a2.z * cr + w * v2.z; a2.w = a2.w * cr + w * v2.w;
        a3.x = a3.x * cr + w * v3.x; a3.y = a3.y * cr + w * v3.y;
        a3.z = a3.z * cr + w * v3.z; a3.w = a3.w * cr + w * v3.w;
    }

    float inv = (dg > 0) ? 1.f / sum : 0.f;
    float* orow = aggout + (size_t)g * 128 + h * 16;
    a0.x *= inv; a0.y *= inv; a0.z *= inv; a0.w *= inv;
    a1.x *= inv; a1.y *= inv; a1.z *= inv; a1.w *= inv;
    a2.x *= inv; a2.y *= inv; a2.z *= inv; a2.w *= inv;
    a3.x *= inv; a3.y *= inv; a3.z *= inv; a3.w *= inv;
    *(float4*)(orow) = a0;
    *(float4*)(orow + 4) = a1;
    *(float4*)(orow + 8) = a2;
    *(float4*)(orow + 12) = a3;
}

// ============================================================================
extern "C" void kernel_launch(void* const* d_in, const int* in_sizes, int n_in,
                              void* d_out, int out_size, void* d_ws, size_t ws_size,
                              hipStream_t stream)
{
    const float* h_item = (const float*)d_in[0];
    const float* h_user = (const float*)d_in[1];
    const float* Wk  = (const float*)d_in[2];
    const float* bk  = (const float*)d_in[3];
    const float* Wq  = (const float*)d_in[4];
    const float* bq  = (const float*)d_in[5];
    const float* Wv  = (const float*)d_in[6];
    const float* bv  = (const float*)d_in[7];
    const float* Wa  = (const float*)d_in[8];
    const float* ba  = (const float*)d_in[9];
    const float* rel_pri = (const float*)d_in[10];
    const float* rel_att = (const float*)d_in[11];
    const float* rel_msg = (const float*)d_in[12];
    const float* skipv   = (const float*)d_in[13];
    const int* s0 = (const int*)d_in[14]; const int* d0 = (const int*)d_in[15];
    const int* s1 = (const int*)d_in[16]; const int* d1 = (const int*)d_in[17];
    const int* s2 = (const int*)d_in[18]; const int* d2 = (const int*)d_in[19];
    const int E0 = in_sizes[14], E1 = in_sizes[16], E2 = in_sizes[18];
    const int Etot = E0 + E1 + E2;

    // ws layout (floats): 5 node matrices + small weights + CSR ints (~262 MB).
    // qt0 aliases out_user, qt2 aliases out_item (d_out is scratch until the
    // final GEMMs, which are read-before-write safe per block).
    float* ws = (float*)d_ws;
    float* kb_i = ws;
    float* vb_i = ws + NM;
    float* kb_u = ws + 2 * NM;
    float* vb_u = ws + 3 * NM;
    float* qt1  = ws + 4 * NM;
    float* wreg = ws + 5 * NM;
    float* B_item    = wreg;                   // 49152
    float* bias_item = wreg + 49152;           // 384
    float* B_user    = wreg + 49536;           // 65536
    float* bias_user = wreg + 115072;          // 512
    float* Wfin      = wreg + 115584;          // 3*16384 = 49152
    int* ibuf = (int*)(wreg + 115584 + 49152);
    int* cnt  = ibuf;                          // 3*NN
    int* pos  = ibuf + 3 * NN;                 // 3*NN
    int* offs = ibuf + 6 * NN;                 // 3*NN
    int* psum = ibuf + 9 * NN;                 // 512
    int* csrc = ibuf + 9 * NN + 512;           // Etot (1,000,000)

    float* out_item = (float*)d_out;           // doubles as qt2 / agg2
    float* out_user = (float*)d_out + NM;      // doubles as qt0 / agg0

    prep_weights<<<644, 256, 0, stream>>>(Wk, bk, Wq, bq, Wv, bv, Wa, rel_pri,
                                          rel_att, rel_msg,
                                          B_item, bias_item, B_user, bias_user, Wfin);

    const int tiles = (NN + 127) / 128;        // 782
    OutPtrs oi; oi.p[0] = kb_i; oi.p[1] = vb_i; oi.p[2] = out_item; oi.p[3] = nullptr;
    OutPtrs ou; ou.p[0] = kb_u; ou.p[1] = vb_u; ou.p[2] = out_user; ou.p[3] = qt1;
    gemm_node<<<dim3(tiles, 3), 256, 0, stream>>>(h_item, B_item, bias_item, oi, NN, 384);
    gemm_node<<<dim3(tiles, 4), 256, 0, stream>>>(h_user, B_user, bias_user, ou, NN, 512);

    // CSR build (fused over etypes)
    zero_int<<<(6 * NN + 255) / 256, 256, 0, stream>>>(ibuf, 6 * NN);  // cnt+pos
    hist3<<<(Etot + 255) / 256, 256, 0, stream>>>(d0, d1, d2, E0, E1, E2, cnt);
    const int nscan = 3 * NN;
    const int nb1024 = (nscan + 1023) / 1024;  // 293
    scan1<<<nb1024, 1024, 0, stream>>>(cnt, offs, psum, nscan);
    scan2<<<1, 512, 0, stream>>>(psum, nb1024);
    scan3<<<(nscan + 255) / 256, 256, 0, stream>>>(offs, psum, nscan);
    scatter3<<<(Etot + 255) / 256, 256, 0, stream>>>(s0, d0, s1, d1, s2, d2,
                                                     E0, E1, E2, offs, pos, csrc);

    // attention + aggregation per etype (agg aliases qt)
    const int gblocks = (NN + 31) / 32;        // 3125
    edge_attn<<<gblocks, 256, 0, stream>>>(out_user, kb_i, vb_i,
                                           offs,          cnt,          csrc, out_user);
    edge_attn<<<gblocks, 256, 0, stream>>>(qt1,      kb_i, vb_i,
                                           offs + NN,     cnt + NN,     csrc, qt1);
    edge_attn<<<gblocks, 256, 0, stream>>>(out_item, kb_u, vb_u,
                                           offs + 2 * NN, cnt + 2 * NN, csrc, out_item);

    gemm_final<<<tiles, 256, 0, stream>>>(out_item, nullptr, Wfin, nullptr,
                                          ba, skipv, 0, h_item, out_item, NN);
    gemm_final<<<tiles, 256, 0, stream>>>(out_user, qt1, Wfin + 16384, Wfin + 2 * 16384,
                                          ba + 128, skipv, 1, h_user, out_user, NN);
}

// Round 6
// 992.318 us; speedup vs baseline: 1.7348x; 1.0307x over previous
//
#include <hip/hip_runtime.h>
#include <math.h>

#define NN 100000
#define NM ((size_t)NN * 128)

// ============================================================================
// prep_weights: build effective weight matrices (all tiny)
//  B_item [128][384]: Wk[0] | Wv[0] | Wq[0]@BD(A2)^T * pri2/4
//  B_user [128][512]: Wk[1] | Wv[1] | Wq[1]@BD(A0)^T*pri0/4 | Wq[1]@BD(A1)^T*pri1/4
//  Wfin[0] = BD(M2)@Wa[0]; Wfin[1] = 0.5*BD(M0)@Wa[1]; Wfin[2] = 0.5*BD(M1)@Wa[1]
// ============================================================================
__global__ void prep_weights(
    const float* __restrict__ Wk, const float* __restrict__ bk,
    const float* __restrict__ Wq, const float* __restrict__ bq,
    const float* __restrict__ Wv, const float* __restrict__ bv,
    const float* __restrict__ Wa, const float* __restrict__ rel_pri,
    const float* __restrict__ rel_att, const float* __restrict__ rel_msg,
    float* __restrict__ B_item, float* __restrict__ bias_item,
    float* __restrict__ B_user, float* __restrict__ bias_user,
    float* __restrict__ Wfin)
{
    int t = blockIdx.x * 256 + threadIdx.x;

    if (t < 128 * 384) {                       // B_item
        int k = t / 384, c = t % 384;
        float v;
        if (c < 128)      v = Wk[k * 128 + c];
        else if (c < 256) v = Wv[k * 128 + (c - 128)];
        else {
            int cc = c - 256, h = cc >> 4, d = cc & 15;
            const float* A = rel_att + 2 * 2048 + h * 256 + d * 16;  // A2[h][d][:]
            const float* w = Wq + k * 128 + h * 16;
            float s = 0.f;
            #pragma unroll
            for (int e = 0; e < 16; ++e) s += w[e] * A[e];
            v = s * (rel_pri[16 + h] * 0.25f);
        }
        B_item[k * 384 + c] = v;
        return;
    }
    t -= 128 * 384;
    if (t < 384) {                             // bias_item
        int c = t; float v;
        if (c < 128)      v = bk[c];
        else if (c < 256) v = bv[c - 128];
        else {
            int cc = c - 256, h = cc >> 4, d = cc & 15;
            const float* A = rel_att + 2 * 2048 + h * 256 + d * 16;
            const float* b = bq + h * 16;
            float s = 0.f;
            #pragma unroll
            for (int e = 0; e < 16; ++e) s += b[e] * A[e];
            v = s * (rel_pri[16 + h] * 0.25f);
        }
        bias_item[c] = v;
        return;
    }
    t -= 384;
    if (t < 128 * 512) {                       // B_user
        int k = t / 512, c = t % 512;
        float v;
        if (c < 128)      v = Wk[16384 + k * 128 + c];
        else if (c < 256) v = Wv[16384 + k * 128 + (c - 128)];
        else {
            int rr = (c < 384) ? 0 : 1;
            int cc = (c - 256) & 127, h = cc >> 4, d = cc & 15;
            const float* A = rel_att + rr * 2048 + h * 256 + d * 16;
            const float* w = Wq + 16384 + k * 128 + h * 16;
            float s = 0.f;
            #pragma unroll
            for (int e = 0; e < 16; ++e) s += w[e] * A[e];
            v = s * (rel_pri[rr * 8 + h] * 0.25f);
        }
        B_user[k * 512 + c] = v;
        return;
    }
    t -= 128 * 512;
    if (t < 512) {                             // bias_user
        int c = t; float v;
        if (c < 128)      v = bk[128 + c];
        else if (c < 256) v = bv[128 + c - 128];
        else {
            int rr = (c < 384) ? 0 : 1;
            int cc = (c - 256) & 127, h = cc >> 4, d = cc & 15;
            const float* A = rel_att + rr * 2048 + h * 256 + d * 16;
            const float* b = bq + 128 + h * 16;
            float s = 0.f;
            #pragma unroll
            for (int e = 0; e < 16; ++e) s += b[e] * A[e];
            v = s * (rel_pri[rr * 8 + h] * 0.25f);
        }
        bias_user[c] = v;
        return;
    }
    t -= 512;
    if (t < 3 * 16384) {                       // Wfin
        int which = t / 16384, rem = t % 16384;
        int rin = rem / 128, c = rem % 128;
        int h = rin >> 4, d = rin & 15;
        const float* M; const float* W; float scale;
        if (which == 0)      { M = rel_msg + 2 * 2048 + h * 256 + d * 16; W = Wa;         scale = 1.0f; }
        else if (which == 1) { M = rel_msg + 0        + h * 256 + d * 16; W = Wa + 16384; scale = 0.5f; }
        else                 { M = rel_msg + 2048     + h * 256 + d * 16; W = Wa + 16384; scale = 0.5f; }
        float s = 0.f;
        #pragma unroll
        for (int e = 0; e < 16; ++e) s += M[e] * W[(h * 16 + e) * 128 + c];
        Wfin[which * 16384 + rin * 128 + c] = s * scale;
    }
}

// ============================================================================
// Shared GEMM tile body: 128x128 tile, BK=32, 8x8 per thread.
// As padded to 36 floats/row: per-wave a4 b128 reads hit disjoint bank quads.
// a4[8][4] statically indexed (unrolled) -> stays in VGPRs.
// __launch_bounds__(256) only — (256,4) caused a 64-VGPR cap + acc spill (r3).
// ============================================================================
#define GEMM_TILE_BODY(BPTR, BSTRIDE, APTR)                                    \
    for (int ks = 0; ks < 128; ks += 32) {                                     \
        __syncthreads();                                                       \
        _Pragma("unroll")                                                      \
        for (int it = 0; it < 4; ++it) {                                       \
            int f = tid + it * 256;                                            \
            int k = f >> 5, lc4 = f & 31;                                      \
            *(float4*)(Bs + k * 128 + lc4 * 4) =                               \
                *(const float4*)(BPTR + (size_t)(ks + k) * BSTRIDE + lc4 * 4); \
        }                                                                      \
        _Pragma("unroll")                                                      \
        for (int it = 0; it < 4; ++it) {                                       \
            int f = tid + it * 256;                                            \
            int row = f >> 3, kk4 = f & 7;                                     \
            int r = tile * 128 + row;                                          \
            float4 v = make_float4(0.f, 0.f, 0.f, 0.f);                        \
            if (r < NN) v = *(const float4*)(APTR + (size_t)r * 128 + ks + kk4 * 4); \
            *(float4*)(As + row * 36 + kk4 * 4) = v;                           \
        }                                                                      \
        __syncthreads();                                                       \
        _Pragma("unroll")                                                      \
        for (int kq = 0; kq < 8; ++kq) {                                       \
            float a4[8][4];                                                    \
            _Pragma("unroll")                                                  \
            for (int i = 0; i < 8; ++i)                                        \
                *(float4*)a4[i] = *(const float4*)(As + (ty + 16 * i) * 36 + kq * 4); \
            _Pragma("unroll")                                                  \
            for (int j = 0; j < 4; ++j) {                                      \
                int kk = kq * 4 + j;                                           \
                float4 b0 = *(const float4*)(Bs + kk * 128 + tx * 4);          \
                float4 b1 = *(const float4*)(Bs + kk * 128 + 64 + tx * 4);     \
                _Pragma("unroll")                                              \
                for (int i = 0; i < 8; ++i) {                                  \
                    float a = a4[i][j];                                        \
                    acc[i][0] += a * b0.x; acc[i][1] += a * b0.y;              \
                    acc[i][2] += a * b0.z; acc[i][3] += a * b0.w;              \
                    acc[i][4] += a * b1.x; acc[i][5] += a * b1.y;              \
                    acc[i][6] += a * b1.z; acc[i][7] += a * b1.w;              \
                }                                                              \
            }                                                                  \
        }                                                                      \
    }

// ============================================================================
// gemm_node: 7 independent 100k x 128 x 128 slab-GEMMs in ONE dispatch.
// gy 0..2: item (Wk|Wv|Wq'A2); gy 3..6: user (Wk|Wv|Wq'A0|Wq'A1).
// ============================================================================
struct NodeParams {
    const float* A[7];
    const float* Bcol[7];     // slab column base
    const float* biasc[7];    // bias + column offset
    float* out[7];
    int stride[7];
};

__global__ __launch_bounds__(256) void gemm_node(NodeParams P)
{
    __shared__ float Bs[32 * 128];
    __shared__ float As[128 * 36];
    const int tid = threadIdx.x;
    const int gy = blockIdx.y;
    const int tile = blockIdx.x;
    const int tx = tid & 15, ty = tid >> 4;

    const float* A = P.A[gy];
    const float* B = P.Bcol[gy];
    const int Bstride = P.stride[gy];

    float acc[8][8];
    #pragma unroll
    for (int i = 0; i < 8; ++i)
        #pragma unroll
        for (int j = 0; j < 8; ++j) acc[i][j] = 0.f;

    GEMM_TILE_BODY(B, Bstride, A)

    const float* bias = P.biasc[gy];
    float4 bi0 = *(const float4*)(bias + tx * 4);
    float4 bi1 = *(const float4*)(bias + 64 + tx * 4);
    float* out = P.out[gy];
    #pragma unroll
    for (int i = 0; i < 8; ++i) {
        int r = tile * 128 + ty + 16 * i;
        if (r < NN) {
            float4 o0 = make_float4(acc[i][0] + bi0.x, acc[i][1] + bi0.y,
                                    acc[i][2] + bi0.z, acc[i][3] + bi0.w);
            float4 o1 = make_float4(acc[i][4] + bi1.x, acc[i][5] + bi1.y,
                                    acc[i][6] + bi1.z, acc[i][7] + bi1.w);
            *(float4*)(out + (size_t)r * 128 + tx * 4) = o0;
            *(float4*)(out + (size_t)r * 128 + 64 + tx * 4) = o1;
        }
    }
}

// ============================================================================
// gemm_final: gy=0 item (1 pass), gy=1 user (2 passes summed).
// out = (sum_p A_p@B_p + ba) * alpha + hin * (1-alpha).
// A may alias out: each block only reads the rows it later writes.
// ============================================================================
struct FinParams {
    const float* A0[2]; const float* A1[2];
    const float* B0[2]; const float* B1[2];
    const float* ba[2]; const float* hin[2];
    float* out[2];
};

__global__ __launch_bounds__(256) void gemm_final(FinParams P, const float* __restrict__ skipv)
{
    __shared__ float Bs[32 * 128];
    __shared__ float As[128 * 36];
    const int tid = threadIdx.x;
    const int gy = blockIdx.y;
    const int tile = blockIdx.x;
    const int tx = tid & 15, ty = tid >> 4;

    float acc[8][8];
    #pragma unroll
    for (int i = 0; i < 8; ++i)
        #pragma unroll
        for (int j = 0; j < 8; ++j) acc[i][j] = 0.f;

    const float* Ap[2] = { P.A0[gy], P.A1[gy] };
    const float* Bp[2] = { P.B0[gy], P.B1[gy] };
    const int nA = (Ap[1] != nullptr) ? 2 : 1;

    for (int p = 0; p < nA; ++p) {
        const float* Acur = Ap[p];
        const float* Bcur = Bp[p];
        GEMM_TILE_BODY(Bcur, 128, Acur)
    }

    float sv = skipv[gy];
    float alpha = 1.f / (1.f + __expf(-sv));
    float beta = 1.f - alpha;
    const float* ba = P.ba[gy];
    const float* hin = P.hin[gy];
    float* out = P.out[gy];
    float4 ba0 = *(const float4*)(ba + tx * 4);
    float4 ba1 = *(const float4*)(ba + 64 + tx * 4);
    #pragma unroll
    for (int i = 0; i < 8; ++i) {
        int r = tile * 128 + ty + 16 * i;
        if (r < NN) {
            float4 h0 = *(const float4*)(hin + (size_t)r * 128 + tx * 4);
            float4 h1 = *(const float4*)(hin + (size_t)r * 128 + 64 + tx * 4);
            float4 o0 = make_float4((acc[i][0] + ba0.x) * alpha + h0.x * beta,
                                    (acc[i][1] + ba0.y) * alpha + h0.y * beta,
                                    (acc[i][2] + ba0.z) * alpha + h0.z * beta,
                                    (acc[i][3] + ba0.w) * alpha + h0.w * beta);
            float4 o1 = make_float4((acc[i][4] + ba1.x) * alpha + h1.x * beta,
                                    (acc[i][5] + ba1.y) * alpha + h1.y * beta,
                                    (acc[i][6] + ba1.z) * alpha + h1.z * beta,
                                    (acc[i][7] + ba1.w) * alpha + h1.w * beta);
            *(float4*)(out + (size_t)r * 128 + tx * 4) = o0;
            *(float4*)(out + (size_t)r * 128 + 64 + tx * 4) = o1;
        }
    }
}

// ============================================================================
// CSR build — fused across the 3 etypes (cnt/pos/offs are [3][NN]; single
// global scan; offs indexes the single 1M csrc buffer).
// ============================================================================
__global__ void zero_int(int* __restrict__ p, int n) {
    int i = blockIdx.x * 256 + threadIdx.x;
    if (i < n) p[i] = 0;
}
__global__ void hist3(const int* __restrict__ d0, const int* __restrict__ d1,
                      const int* __restrict__ d2, int E0, int E1, int E2,
                      int* __restrict__ cnt) {
    int e = blockIdx.x * 256 + threadIdx.x;
    int g;
    if (e < E0) g = 0 * NN + d0[e];
    else if (e < E0 + E1) g = 1 * NN + d1[e - E0];
    else if (e < E0 + E1 + E2) g = 2 * NN + d2[e - E0 - E1];
    else return;
    atomicAdd(&cnt[g], 1);
}
__global__ void scan1(const int* __restrict__ cnt, int* __restrict__ offs,
                      int* __restrict__ psum, int n) {
    __shared__ int sm[1024];
    int t = threadIdx.x, i = blockIdx.x * 1024 + t;
    int v = (i < n) ? cnt[i] : 0;
    sm[t] = v; __syncthreads();
    for (int off = 1; off < 1024; off <<= 1) {
        int x = (t >= off) ? sm[t - off] : 0;
        __syncthreads();
        sm[t] += x;
        __syncthreads();
    }
    if (i < n) offs[i] = sm[t] - v;           // exclusive
    if (t == 1023) psum[blockIdx.x] = sm[1023];
}
__global__ void scan2(int* __restrict__ psum, int nb) {
    __shared__ int sm[512];
    int t = threadIdx.x;
    int v = (t < nb) ? psum[t] : 0;
    sm[t] = v; __syncthreads();
    for (int off = 1; off < 512; off <<= 1) {
        int x = (t >= off) ? sm[t - off] : 0;
        __syncthreads();
        sm[t] += x;
        __syncthreads();
    }
    if (t < nb) psum[t] = sm[t] - v;
}
__global__ void scan3(int* __restrict__ offs, const int* __restrict__ psum, int n) {
    int i = blockIdx.x * 256 + threadIdx.x;
    if (i < n) offs[i] += psum[i >> 10];
}
__global__ void scatter3(const int* __restrict__ s0, const int* __restrict__ d0,
                         const int* __restrict__ s1, const int* __restrict__ d1,
                         const int* __restrict__ s2, const int* __restrict__ d2,
                         int E0, int E1, int E2,
                         const int* __restrict__ offs, int* __restrict__ pos,
                         int* __restrict__ csrc) {
    int e = blockIdx.x * 256 + threadIdx.x;
    int g, s;
    if (e < E0) { g = 0 * NN + d0[e]; s = s0[e]; }
    else if (e < E0 + E1) { int l = e - E0; g = 1 * NN + d1[l]; s = s1[l]; }
    else if (e < E0 + E1 + E2) { int l = e - E0 - E1; g = 2 * NN + d2[l]; s = s2[l]; }
    else return;
    int p = atomicAdd(&pos[g], 1);
    csrc[offs[g] + p] = s;
}

// ============================================================================
// edge_attn: all 3 etypes in one dispatch (blockIdx.y = r). One 8-lane group
// per dst node, lane = head. Online softmax; pri/sqrt(dk) pre-folded into qt.
// agg aliases qt (row fully read into regs before overwrite).
// ============================================================================
struct EdgeParams {
    const float* qt[3];
    const float* kb[3];
    const float* vb[3];
    float* agg[3];
};

__global__ __launch_bounds__(256) void edge_attn(
    EdgeParams P, const int* __restrict__ offs, const int* __restrict__ deg,
    const int* __restrict__ csrc)
{
    int r = blockIdx.y;
    int g = blockIdx.x * 32 + (threadIdx.x >> 3);
    int h = threadIdx.x & 7;
    if (g >= NN) return;

    const float* qt = P.qt[r];
    const float* kb = P.kb[r];
    const float* vb = P.vb[r];

    const float* qrow = qt + (size_t)g * 128 + h * 16;
    float4 q0 = *(const float4*)(qrow);
    float4 q1 = *(const float4*)(qrow + 4);
    float4 q2 = *(const float4*)(qrow + 8);
    float4 q3 = *(const float4*)(qrow + 12);

    int s = offs[r * NN + g], dg = deg[r * NN + g];
    float m = -__builtin_inff(), sum = 0.f;
    float4 a0 = make_float4(0, 0, 0, 0), a1 = a0, a2 = a0, a3 = a0;

    for (int e = 0; e < dg; ++e) {
        int src = csrc[s + e];
        const float* krow = kb + (size_t)src * 128 + h * 16;
        float4 k0 = *(const float4*)(krow);
        float4 k1 = *(const float4*)(krow + 4);
        float4 k2 = *(const float4*)(krow + 8);
        float4 k3 = *(const float4*)(krow + 12);
        float sc = q0.x * k0.x + q0.y * k0.y + q0.z * k0.z + q0.w * k0.w
                 + q1.x * k1.x + q1.y * k1.y + q1.z * k1.z + q1.w * k1.w
                 + q2.x * k2.x + q2.y * k2.y + q2.z * k2.z + q2.w * k2.w
                 + q3.x * k3.x + q3.y * k3.y + q3.z * k3.z + q3.w * k3.w;
        float mn = fmaxf(m, sc);
        float cr = __expf(m - mn);            // 0 on first edge (m = -inf)
        float w = __expf(sc - mn);
        sum = sum * cr + w;
        m = mn;
        const float* vrow = vb + (size_t)src * 128 + h * 16;
        float4 v0 = *(const float4*)(vrow);
        float4 v1 = *(const float4*)(vrow + 4);
        float4 v2 = *(const float4*)(vrow + 8);
        float4 v3 = *(const float4*)(vrow + 12);
        a0.x = a0.x * cr + w * v0.x; a0.y = a0.y * cr + w * v0.y;
        a0.z = a0.z * cr + w * v0.z; a0.w = a0.w * cr + w * v0.w;
        a1.x = a1.x * cr + w * v1.x; a1.y = a1.y * cr + w * v1.y;
        a1.z = a1.z * cr + w * v1.z; a1.w = a1.w * cr + w * v1.w;
        a2.x = a2.x * cr + w * v2.x; a2.y = a2.y * cr + w * v2.y;
        a2.z = a2.z * cr + w * v2.z; a2.w = a2.w * cr + w * v2.w;
        a3.x = a3.x * cr + w * v3.x; a3.y = a3.y * cr + w * v3.y;
        a3.z = a3.z * cr + w * v3.z; a3.w = a3.w * cr + w * v3.w;
    }

    float inv = (dg > 0) ? 1.f / sum : 0.f;
    float* orow = P.agg[r] + (size_t)g * 128 + h * 16;
    a0.x *= inv; a0.y *= inv; a0.z *= inv; a0.w *= inv;
    a1.x *= inv; a1.y *= inv; a1.z *= inv; a1.w *= inv;
    a2.x *= inv; a2.y *= inv; a2.z *= inv; a2.w *= inv;
    a3.x *= inv; a3.y *= inv; a3.z *= inv; a3.w *= inv;
    *(float4*)(orow) = a0;
    *(float4*)(orow + 4) = a1;
    *(float4*)(orow + 8) = a2;
    *(float4*)(orow + 12) = a3;
}

// ============================================================================
extern "C" void kernel_launch(void* const* d_in, const int* in_sizes, int n_in,
                              void* d_out, int out_size, void* d_ws, size_t ws_size,
                              hipStream_t stream)
{
    const float* h_item = (const float*)d_in[0];
    const float* h_user = (const float*)d_in[1];
    const float* Wk  = (const float*)d_in[2];
    const float* bk  = (const float*)d_in[3];
    const float* Wq  = (const float*)d_in[4];
    const float* bq  = (const float*)d_in[5];
    const float* Wv  = (const float*)d_in[6];
    const float* bv  = (const float*)d_in[7];
    const float* Wa  = (const float*)d_in[8];
    const float* ba  = (const float*)d_in[9];
    const float* rel_pri = (const float*)d_in[10];
    const float* rel_att = (const float*)d_in[11];
    const float* rel_msg = (const float*)d_in[12];
    const float* skipv   = (const float*)d_in[13];
    const int* s0 = (const int*)d_in[14]; const int* d0 = (const int*)d_in[15];
    const int* s1 = (const int*)d_in[16]; const int* d1 = (const int*)d_in[17];
    const int* s2 = (const int*)d_in[18]; const int* d2 = (const int*)d_in[19];
    const int E0 = in_sizes[14], E1 = in_sizes[16], E2 = in_sizes[18];
    const int Etot = E0 + E1 + E2;

    // ws layout: 5 node matrices + small weights + CSR ints (~262 MB).
    // qt0 aliases out_user, qt2 aliases out_item.
    float* ws = (float*)d_ws;
    float* kb_i = ws;
    float* vb_i = ws + NM;
    float* kb_u = ws + 2 * NM;
    float* vb_u = ws + 3 * NM;
    float* qt1  = ws + 4 * NM;
    float* wreg = ws + 5 * NM;
    float* B_item    = wreg;                   // 49152
    float* bias_item = wreg + 49152;           // 384
    float* B_user    = wreg + 49536;           // 65536
    float* bias_user = wreg + 115072;          // 512
    float* Wfin      = wreg + 115584;          // 3*16384 = 49152
    int* ibuf = (int*)(wreg + 115584 + 49152);
    int* cnt  = ibuf;                          // 3*NN
    int* pos  = ibuf + 3 * NN;                 // 3*NN
    int* offs = ibuf + 6 * NN;                 // 3*NN
    int* psum = ibuf + 9 * NN;                 // 512
    int* csrc = ibuf + 9 * NN + 512;           // Etot (1,000,000)

    float* out_item = (float*)d_out;           // doubles as qt2 / agg2
    float* out_user = (float*)d_out + NM;      // doubles as qt0 / agg0

    prep_weights<<<644, 256, 0, stream>>>(Wk, bk, Wq, bq, Wv, bv, Wa, rel_pri,
                                          rel_att, rel_msg,
                                          B_item, bias_item, B_user, bias_user, Wfin);

    const int tiles = (NN + 127) / 128;        // 782

    NodeParams np;
    for (int gy = 0; gy < 3; ++gy) {
        np.A[gy] = h_item; np.Bcol[gy] = B_item + gy * 128;
        np.biasc[gy] = bias_item + gy * 128; np.stride[gy] = 384;
    }
    for (int gy = 3; gy < 7; ++gy) {
        np.A[gy] = h_user; np.Bcol[gy] = B_user + (gy - 3) * 128;
        np.biasc[gy] = bias_user + (gy - 3) * 128; np.stride[gy] = 512;
    }
    np.out[0] = kb_i; np.out[1] = vb_i; np.out[2] = out_item;
    np.out[3] = kb_u; np.out[4] = vb_u; np.out[5] = out_user; np.out[6] = qt1;
    gemm_node<<<dim3(tiles, 7), 256, 0, stream>>>(np);

    // CSR build (fused over etypes)
    zero_int<<<(6 * NN + 255) / 256, 256, 0, stream>>>(ibuf, 6 * NN);  // cnt+pos
    hist3<<<(Etot + 255) / 256, 256, 0, stream>>>(d0, d1, d2, E0, E1, E2, cnt);
    const int nscan = 3 * NN;
    const int nb1024 = (nscan + 1023) / 1024;  // 293
    scan1<<<nb1024, 1024, 0, stream>>>(cnt, offs, psum, nscan);
    scan2<<<1, 512, 0, stream>>>(psum, nb1024);
    scan3<<<(nscan + 255) / 256, 256, 0, stream>>>(offs, psum, nscan);
    scatter3<<<(Etot + 255) / 256, 256, 0, stream>>>(s0, d0, s1, d1, s2, d2,
                                                     E0, E1, E2, offs, pos, csrc);

    // attention + aggregation, all 3 etypes in one dispatch (agg aliases qt)
    EdgeParams ep;
    ep.qt[0] = out_user; ep.kb[0] = kb_i; ep.vb[0] = vb_i; ep.agg[0] = out_user;
    ep.qt[1] = qt1;      ep.kb[1] = kb_i; ep.vb[1] = vb_i; ep.agg[1] = qt1;
    ep.qt[2] = out_item; ep.kb[2] = kb_u; ep.vb[2] = vb_u; ep.agg[2] = out_item;
    edge_attn<<<dim3((NN + 31) / 32, 3), 256, 0, stream>>>(ep, offs, cnt, csrc);

    FinParams fp;
    fp.A0[0] = out_item; fp.A1[0] = nullptr;
    fp.B0[0] = Wfin;     fp.B1[0] = nullptr;
    fp.ba[0] = ba;       fp.hin[0] = h_item; fp.out[0] = out_item;
    fp.A0[1] = out_user; fp.A1[1] = qt1;
    fp.B0[1] = Wfin + 16384; fp.B1[1] = Wfin + 2 * 16384;
    fp.ba[1] = ba + 128; fp.hin[1] = h_user; fp.out[1] = out_user;
    gemm_final<<<dim3(tiles, 2), 256, 0, stream>>>(fp, skipv);
}

// Round 8
// 955.705 us; speedup vs baseline: 1.8013x; 1.0383x over previous
//
#include <hip/hip_runtime.h>
#include <math.h>

#define NN 100000
#define NM ((size_t)NN * 128)

// ============================================================================
// prep_weights: build effective weight matrices (all tiny)
//  B_item [128][384]: Wk[0] | Wv[0] | Wq[0]@BD(A2)^T * pri2/4
//  B_user [128][512]: Wk[1] | Wv[1] | Wq[1]@BD(A0)^T*pri0/4 | Wq[1]@BD(A1)^T*pri1/4
//  Wfin[0] = BD(M2)@Wa[0]; Wfin[1] = 0.5*BD(M0)@Wa[1]; Wfin[2] = 0.5*BD(M1)@Wa[1]
// ============================================================================
__global__ void prep_weights(
    const float* __restrict__ Wk, const float* __restrict__ bk,
    const float* __restrict__ Wq, const float* __restrict__ bq,
    const float* __restrict__ Wv, const float* __restrict__ bv,
    const float* __restrict__ Wa, const float* __restrict__ rel_pri,
    const float* __restrict__ rel_att, const float* __restrict__ rel_msg,
    float* __restrict__ B_item, float* __restrict__ bias_item,
    float* __restrict__ B_user, float* __restrict__ bias_user,
    float* __restrict__ Wfin)
{
    int t = blockIdx.x * 256 + threadIdx.x;

    if (t < 128 * 384) {                       // B_item
        int k = t / 384, c = t % 384;
        float v;
        if (c < 128)      v = Wk[k * 128 + c];
        else if (c < 256) v = Wv[k * 128 + (c - 128)];
        else {
            int cc = c - 256, h = cc >> 4, d = cc & 15;
            const float* A = rel_att + 2 * 2048 + h * 256 + d * 16;  // A2[h][d][:]
            const float* w = Wq + k * 128 + h * 16;
            float s = 0.f;
            #pragma unroll
            for (int e = 0; e < 16; ++e) s += w[e] * A[e];
            v = s * (rel_pri[16 + h] * 0.25f);
        }
        B_item[k * 384 + c] = v;
        return;
    }
    t -= 128 * 384;
    if (t < 384) {                             // bias_item
        int c = t; float v;
        if (c < 128)      v = bk[c];
        else if (c < 256) v = bv[c - 128];
        else {
            int cc = c - 256, h = cc >> 4, d = cc & 15;
            const float* A = rel_att + 2 * 2048 + h * 256 + d * 16;
            const float* b = bq + h * 16;
            float s = 0.f;
            #pragma unroll
            for (int e = 0; e < 16; ++e) s += b[e] * A[e];
            v = s * (rel_pri[16 + h] * 0.25f);
        }
        bias_item[c] = v;
        return;
    }
    t -= 384;
    if (t < 128 * 512) {                       // B_user
        int k = t / 512, c = t % 512;
        float v;
        if (c < 128)      v = Wk[16384 + k * 128 + c];
        else if (c < 256) v = Wv[16384 + k * 128 + (c - 128)];
        else {
            int rr = (c < 384) ? 0 : 1;
            int cc = (c - 256) & 127, h = cc >> 4, d = cc & 15;
            const float* A = rel_att + rr * 2048 + h * 256 + d * 16;
            const float* w = Wq + 16384 + k * 128 + h * 16;
            float s = 0.f;
            #pragma unroll
            for (int e = 0; e < 16; ++e) s += w[e] * A[e];
            v = s * (rel_pri[rr * 8 + h] * 0.25f);
        }
        B_user[k * 512 + c] = v;
        return;
    }
    t -= 128 * 512;
    if (t < 512) {                             // bias_user
        int c = t; float v;
        if (c < 128)      v = bk[128 + c];
        else if (c < 256) v = bv[128 + c - 128];
        else {
            int rr = (c < 384) ? 0 : 1;
            int cc = (c - 256) & 127, h = cc >> 4, d = cc & 15;
            const float* A = rel_att + rr * 2048 + h * 256 + d * 16;
            const float* b = bq + 128 + h * 16;
            float s = 0.f;
            #pragma unroll
            for (int e = 0; e < 16; ++e) s += b[e] * A[e];
            v = s * (rel_pri[rr * 8 + h] * 0.25f);
        }
        bias_user[c] = v;
        return;
    }
    t -= 512;
    if (t < 3 * 16384) {                       // Wfin
        int which = t / 16384, rem = t % 16384;
        int rin = rem / 128, c = rem % 128;
        int h = rin >> 4, d = rin & 15;
        const float* M; const float* W; float scale;
        if (which == 0)      { M = rel_msg + 2 * 2048 + h * 256 + d * 16; W = Wa;         scale = 1.0f; }
        else if (which == 1) { M = rel_msg + 0        + h * 256 + d * 16; W = Wa + 16384; scale = 0.5f; }
        else                 { M = rel_msg + 2048     + h * 256 + d * 16; W = Wa + 16384; scale = 0.5f; }
        float s = 0.f;
        #pragma unroll
        for (int e = 0; e < 16; ++e) s += M[e] * W[(h * 16 + e) * 128 + c];
        Wfin[which * 16384 + rin * 128 + c] = s * scale;
    }
}

// ============================================================================
// Shared GEMM tile body, v3: 128x128 tile, BK=16, 8x8 per thread.
// Thread (tx,ty): rows ty*8..ty*8+7 (CONTIGUOUS), cols tx*4 & 64+tx*4.
// A staged TRANSPOSED: AsT[kk][row], row length 132 (pad: 132%32=4 makes the
// transpose-scatter 2-way = free, and the 4 per-wave a-read addresses land on
// disjoint bank quads with 16-lane broadcast). Per kk: 2 A-b128 + 2 B-b128 —
// 4 LDS reads vs 10 in the round-5 body (LDS issue was the binding pipe:
// 280 vs 128 FMA cyc per kk per CU -> VALUBusy capped ~60%).
// __launch_bounds__(256) only — (256,4) caused a 64-VGPR cap + acc spill (r3).
// ============================================================================
#define AST_LD 132

#define GEMM_TILE_BODY(BPTR, BSTRIDE, APTR)                                    \
    for (int ks = 0; ks < 128; ks += 16) {                                     \
        __syncthreads();                                                       \
        _Pragma("unroll")                                                      \
        for (int it = 0; it < 2; ++it) {                                       \
            int f = tid + it * 256;                                            \
            int k = f >> 5, lc4 = f & 31;                                      \
            *(float4*)(Bs + k * 128 + lc4 * 4) =                               \
                *(const float4*)(BPTR + (size_t)(ks + k) * BSTRIDE + lc4 * 4); \
        }                                                                      \
        _Pragma("unroll")                                                      \
        for (int it = 0; it < 2; ++it) {                                       \
            int f = tid + it * 256;                                            \
            int row = f >> 2, kq = f & 3;                                      \
            int r = tile * 128 + row;                                          \
            float4 v = make_float4(0.f, 0.f, 0.f, 0.f);                        \
            if (r < NN) v = *(const float4*)(APTR + (size_t)r * 128 + ks + kq * 4); \
            AsT[(kq * 4 + 0) * AST_LD + row] = v.x;                            \
            AsT[(kq * 4 + 1) * AST_LD + row] = v.y;                            \
            AsT[(kq * 4 + 2) * AST_LD + row] = v.z;                            \
            AsT[(kq * 4 + 3) * AST_LD + row] = v.w;                            \
        }                                                                      \
        __syncthreads();                                                       \
        _Pragma("unroll")                                                      \
        for (int kk = 0; kk < 16; ++kk) {                                      \
            float4 a0 = *(const float4*)(AsT + kk * AST_LD + ty * 8);          \
            float4 a1 = *(const float4*)(AsT + kk * AST_LD + ty * 8 + 4);      \
            float4 b0 = *(const float4*)(Bs + kk * 128 + tx * 4);              \
            float4 b1 = *(const float4*)(Bs + kk * 128 + 64 + tx * 4);         \
            float av[8] = { a0.x, a0.y, a0.z, a0.w, a1.x, a1.y, a1.z, a1.w };  \
            _Pragma("unroll")                                                  \
            for (int i = 0; i < 8; ++i) {                                      \
                float a = av[i];                                               \
                acc[i][0] += a * b0.x; acc[i][1] += a * b0.y;                  \
                acc[i][2] += a * b0.z; acc[i][3] += a * b0.w;                  \
                acc[i][4] += a * b1.x; acc[i][5] += a * b1.y;                  \
                acc[i][6] += a * b1.z; acc[i][7] += a * b1.w;                  \
            }                                                                  \
        }                                                                      \
    }

// ============================================================================
// gemm_node: 7 independent 100k x 128 x 128 slab-GEMMs in ONE dispatch.
// gy 0..2: item (Wk|Wv|Wq'A2); gy 3..6: user (Wk|Wv|Wq'A0|Wq'A1).
// ============================================================================
struct NodeParams {
    const float* A[7];
    const float* Bcol[7];     // slab column base
    const float* biasc[7];    // bias + column offset
    float* out[7];
    int stride[7];
};

__global__ __launch_bounds__(256) void gemm_node(NodeParams P)
{
    __shared__ float Bs[16 * 128];
    __shared__ float AsT[16 * AST_LD];
    const int tid = threadIdx.x;
    const int gy = blockIdx.y;
    const int tile = blockIdx.x;
    const int tx = tid & 15, ty = tid >> 4;

    const float* A = P.A[gy];
    const float* B = P.Bcol[gy];
    const int Bstride = P.stride[gy];

    float acc[8][8];
    #pragma unroll
    for (int i = 0; i < 8; ++i)
        #pragma unroll
        for (int j = 0; j < 8; ++j) acc[i][j] = 0.f;

    GEMM_TILE_BODY(B, Bstride, A)

    const float* bias = P.biasc[gy];
    float4 bi0 = *(const float4*)(bias + tx * 4);
    float4 bi1 = *(const float4*)(bias + 64 + tx * 4);
    float* out = P.out[gy];
    #pragma unroll
    for (int i = 0; i < 8; ++i) {
        int r = tile * 128 + ty * 8 + i;
        if (r < NN) {
            float4 o0 = make_float4(acc[i][0] + bi0.x, acc[i][1] + bi0.y,
                                    acc[i][2] + bi0.z, acc[i][3] + bi0.w);
            float4 o1 = make_float4(acc[i][4] + bi1.x, acc[i][5] + bi1.y,
                                    acc[i][6] + bi1.z, acc[i][7] + bi1.w);
            *(float4*)(out + (size_t)r * 128 + tx * 4) = o0;
            *(float4*)(out + (size_t)r * 128 + 64 + tx * 4) = o1;
        }
    }
}

// ============================================================================
// gemm_final: gy=0 item (1 pass), gy=1 user (2 passes summed).
// out = (sum_p A_p@B_p + ba) * alpha + hin * (1-alpha).
// A may alias out: each block only reads rows [tile*128, +128) during staging
// (all before the last barrier) and writes the same rows after compute.
// ============================================================================
struct FinParams {
    const float* A0[2]; const float* A1[2];
    const float* B0[2]; const float* B1[2];
    const float* ba[2]; const float* hin[2];
    float* out[2];
};

__global__ __launch_bounds__(256) void gemm_final(FinParams P, const float* __restrict__ skipv)
{
    __shared__ float Bs[16 * 128];
    __shared__ float AsT[16 * AST_LD];
    const int tid = threadIdx.x;
    const int gy = blockIdx.y;
    const int tile = blockIdx.x;
    const int tx = tid & 15, ty = tid >> 4;

    float acc[8][8];
    #pragma unroll
    for (int i = 0; i < 8; ++i)
        #pragma unroll
        for (int j = 0; j < 8; ++j) acc[i][j] = 0.f;

    const float* Ap[2] = { P.A0[gy], P.A1[gy] };
    const float* Bp[2] = { P.B0[gy], P.B1[gy] };
    const int nA = (Ap[1] != nullptr) ? 2 : 1;

    for (int p = 0; p < nA; ++p) {
        const float* Acur = Ap[p];
        const float* Bcur = Bp[p];
        GEMM_TILE_BODY(Bcur, 128, Acur)
    }

    float sv = skipv[gy];
    float alpha = 1.f / (1.f + __expf(-sv));
    float beta = 1.f - alpha;
    const float* ba = P.ba[gy];
    const float* hin = P.hin[gy];
    float* out = P.out[gy];
    float4 ba0 = *(const float4*)(ba + tx * 4);
    float4 ba1 = *(const float4*)(ba + 64 + tx * 4);
    #pragma unroll
    for (int i = 0; i < 8; ++i) {
        int r = tile * 128 + ty * 8 + i;
        if (r < NN) {
            float4 h0 = *(const float4*)(hin + (size_t)r * 128 + tx * 4);
            float4 h1 = *(const float4*)(hin + (size_t)r * 128 + 64 + tx * 4);
            float4 o0 = make_float4((acc[i][0] + ba0.x) * alpha + h0.x * beta,
                                    (acc[i][1] + ba0.y) * alpha + h0.y * beta,
                                    (acc[i][2] + ba0.z) * alpha + h0.z * beta,
                                    (acc[i][3] + ba0.w) * alpha + h0.w * beta);
            float4 o1 = make_float4((acc[i][4] + ba1.x) * alpha + h1.x * beta,
                                    (acc[i][5] + ba1.y) * alpha + h1.y * beta,
                                    (acc[i][6] + ba1.z) * alpha + h1.z * beta,
                                    (acc[i][7] + ba1.w) * alpha + h1.w * beta);
            *(float4*)(out + (size_t)r * 128 + tx * 4) = o0;
            *(float4*)(out + (size_t)r * 128 + 64 + tx * 4) = o1;
        }
    }
}

// ============================================================================
// CSR build — fused across the 3 etypes (cnt/pos/offs are [3][NN]; single
// global scan; offs indexes the single 1M csrc buffer).
// ============================================================================
__global__ void zero_int(int* __restrict__ p, int n) {
    int i = blockIdx.x * 256 + threadIdx.x;
    if (i < n) p[i] = 0;
}
__global__ void hist3(const int* __restrict__ d0, const int* __restrict__ d1,
                      const int* __restrict__ d2, int E0, int E1, int E2,
                      int* __restrict__ cnt) {
    int e = blockIdx.x * 256 + threadIdx.x;
    int g;
    if (e < E0) g = 0 * NN + d0[e];
    else if (e < E0 + E1) g = 1 * NN + d1[e - E0];
    else if (e < E0 + E1 + E2) g = 2 * NN + d2[e - E0 - E1];
    else return;
    atomicAdd(&cnt[g], 1);
}
__global__ void scan1(const int* __restrict__ cnt, int* __restrict__ offs,
                      int* __restrict__ psum, int n) {
    __shared__ int sm[1024];
    int t = threadIdx.x, i = blockIdx.x * 1024 + t;
    int v = (i < n) ? cnt[i] : 0;
    sm[t] = v; __syncthreads();
    for (int off = 1; off < 1024; off <<= 1) {
        int x = (t >= off) ? sm[t - off] : 0;
        __syncthreads();
        sm[t] += x;
        __syncthreads();
    }
    if (i < n) offs[i] = sm[t] - v;           // exclusive
    if (t == 1023) psum[blockIdx.x] = sm[1023];
}
__global__ void scan2(int* __restrict__ psum, int nb) {
    __shared__ int sm[512];
    int t = threadIdx.x;
    int v = (t < nb) ? psum[t] : 0;
    sm[t] = v; __syncthreads();
    for (int off = 1; off < 512; off <<= 1) {
        int x = (t >= off) ? sm[t - off] : 0;
        __syncthreads();
        sm[t] += x;
        __syncthreads();
    }
    if (t < nb) psum[t] = sm[t] - v;
}
__global__ void scan3(int* __restrict__ offs, const int* __restrict__ psum, int n) {
    int i = blockIdx.x * 256 + threadIdx.x;
    if (i < n) offs[i] += psum[i >> 10];
}
__global__ void scatter3(const int* __restrict__ s0, const int* __restrict__ d0,
                         const int* __restrict__ s1, const int* __restrict__ d1,
                         const int* __restrict__ s2, const int* __restrict__ d2,
                         int E0, int E1, int E2,
                         const int* __restrict__ offs, int* __restrict__ pos,
                         int* __restrict__ csrc) {
    int e = blockIdx.x * 256 + threadIdx.x;
    int g, s;
    if (e < E0) { g = 0 * NN + d0[e]; s = s0[e]; }
    else if (e < E0 + E1) { int l = e - E0; g = 1 * NN + d1[l]; s = s1[l]; }
    else if (e < E0 + E1 + E2) { int l = e - E0 - E1; g = 2 * NN + d2[l]; s = s2[l]; }
    else return;
    int p = atomicAdd(&pos[g], 1);
    csrc[offs[g] + p] = s;
}

// ============================================================================
// edge_attn: all 3 etypes in one dispatch (blockIdx.y = r). One 8-lane group
// per dst node, lane = head. Online softmax; pri/sqrt(dk) pre-folded into qt.
// agg aliases qt (row fully read into regs before overwrite).
// ============================================================================
struct EdgeParams {
    const float* qt[3];
    const float* kb[3];
    const float* vb[3];
    float* agg[3];
};

__global__ __launch_bounds__(256) void edge_attn(
    EdgeParams P, const int* __restrict__ offs, const int* __restrict__ deg,
    const int* __restrict__ csrc)
{
    int r = blockIdx.y;
    int g = blockIdx.x * 32 + (threadIdx.x >> 3);
    int h = threadIdx.x & 7;
    if (g >= NN) return;

    const float* qt = P.qt[r];
    const float* kb = P.kb[r];
    const float* vb = P.vb[r];

    const float* qrow = qt + (size_t)g * 128 + h * 16;
    float4 q0 = *(const float4*)(qrow);
    float4 q1 = *(const float4*)(qrow + 4);
    float4 q2 = *(const float4*)(qrow + 8);
    float4 q3 = *(const float4*)(qrow + 12);

    int s = offs[r * NN + g], dg = deg[r * NN + g];
    float m = -__builtin_inff(), sum = 0.f;
    float4 a0 = make_float4(0, 0, 0, 0), a1 = a0, a2 = a0, a3 = a0;

    for (int e = 0; e < dg; ++e) {
        int src = csrc[s + e];
        const float* krow = kb + (size_t)src * 128 + h * 16;
        float4 k0 = *(const float4*)(krow);
        float4 k1 = *(const float4*)(krow + 4);
        float4 k2 = *(const float4*)(krow + 8);
        float4 k3 = *(const float4*)(krow + 12);
        float sc = q0.x * k0.x + q0.y * k0.y + q0.z * k0.z + q0.w * k0.w
                 + q1.x * k1.x + q1.y * k1.y + q1.z * k1.z + q1.w * k1.w
                 + q2.x * k2.x + q2.y * k2.y + q2.z * k2.z + q2.w * k2.w
                 + q3.x * k3.x + q3.y * k3.y + q3.z * k3.z + q3.w * k3.w;
        float mn = fmaxf(m, sc);
        float cr = __expf(m - mn);            // 0 on first edge (m = -inf)
        float w = __expf(sc - mn);
        sum = sum * cr + w;
        m = mn;
        const float* vrow = vb + (size_t)src * 128 + h * 16;
        float4 v0 = *(const float4*)(vrow);
        float4 v1 = *(const float4*)(vrow + 4);
        float4 v2 = *(const float4*)(vrow + 8);
        float4 v3 = *(const float4*)(vrow + 12);
        a0.x = a0.x * cr + w * v0.x; a0.y = a0.y * cr + w * v0.y;
        a0.z = a0.z * cr + w * v0.z; a0.w = a0.w * cr + w * v0.w;
        a1.x = a1.x * cr + w * v1.x; a1.y = a1.y * cr + w * v1.y;
        a1.z = a1.z * cr + w * v1.z; a1.w = a1.w * cr + w * v1.w;
        a2.x = a2.x * cr + w * v2.x; a2.y = a2.y * cr + w * v2.y;
        a2.z = a2.z * cr + w * v2.z; a2.w = a2.w * cr + w * v2.w;
        a3.x = a3.x * cr + w * v3.x; a3.y = a3.y * cr + w * v3.y;
        a3.z = a3.z * cr + w * v3.z; a3.w = a3.w * cr + w * v3.w;
    }

    float inv = (dg > 0) ? 1.f / sum : 0.f;
    float* orow = P.agg[r] + (size_t)g * 128 + h * 16;
    a0.x *= inv; a0.y *= inv; a0.z *= inv; a0.w *= inv;
    a1.x *= inv; a1.y *= inv; a1.z *= inv; a1.w *= inv;
    a2.x *= inv; a2.y *= inv; a2.z *= inv; a2.w *= inv;
    a3.x *= inv; a3.y *= inv; a3.z *= inv; a3.w *= inv;
    *(float4*)(orow) = a0;
    *(float4*)(orow + 4) = a1;
    *(float4*)(orow + 8) = a2;
    *(float4*)(orow + 12) = a3;
}

// ============================================================================
extern "C" void kernel_launch(void* const* d_in, const int* in_sizes, int n_in,
                              void* d_out, int out_size, void* d_ws, size_t ws_size,
                              hipStream_t stream)
{
    const float* h_item = (const float*)d_in[0];
    const float* h_user = (const float*)d_in[1];
    const float* Wk  = (const float*)d_in[2];
    const float* bk  = (const float*)d_in[3];
    const float* Wq  = (const float*)d_in[4];
    const float* bq  = (const float*)d_in[5];
    const float* Wv  = (const float*)d_in[6];
    const float* bv  = (const float*)d_in[7];
    const float* Wa  = (const float*)d_in[8];
    const float* ba  = (const float*)d_in[9];
    const float* rel_pri = (const float*)d_in[10];
    const float* rel_att = (const float*)d_in[11];
    const float* rel_msg = (const float*)d_in[12];
    const float* skipv   = (const float*)d_in[13];
    const int* s0 = (const int*)d_in[14]; const int* d0 = (const int*)d_in[15];
    const int* s1 = (const int*)d_in[16]; const int* d1 = (const int*)d_in[17];
    const int* s2 = (const int*)d_in[18]; const int* d2 = (const int*)d_in[19];
    const int E0 = in_sizes[14], E1 = in_sizes[16], E2 = in_sizes[18];
    const int Etot = E0 + E1 + E2;

    // ws layout: 5 node matrices + small weights + CSR ints (~262 MB).
    // qt0 aliases out_user, qt2 aliases out_item.
    float* ws = (float*)d_ws;
    float* kb_i = ws;
    float* vb_i = ws + NM;
    float* kb_u = ws + 2 * NM;
    float* vb_u = ws + 3 * NM;
    float* qt1  = ws + 4 * NM;
    float* wreg = ws + 5 * NM;
    float* B_item    = wreg;                   // 49152
    float* bias_item = wreg + 49152;           // 384
    float* B_user    = wreg + 49536;           // 65536
    float* bias_user = wreg + 115072;          // 512
    float* Wfin      = wreg + 115584;          // 3*16384 = 49152
    int* ibuf = (int*)(wreg + 115584 + 49152);
    int* cnt  = ibuf;                          // 3*NN
    int* pos  = ibuf + 3 * NN;                 // 3*NN
    int* offs = ibuf + 6 * NN;                 // 3*NN
    int* psum = ibuf + 9 * NN;                 // 512
    int* csrc = ibuf + 9 * NN + 512;           // Etot (1,000,000)

    float* out_item = (float*)d_out;           // doubles as qt2 / agg2
    float* out_user = (float*)d_out + NM;      // doubles as qt0 / agg0

    prep_weights<<<644, 256, 0, stream>>>(Wk, bk, Wq, bq, Wv, bv, Wa, rel_pri,
                                          rel_att, rel_msg,
                                          B_item, bias_item, B_user, bias_user, Wfin);

    const int tiles = (NN + 127) / 128;        // 782

    NodeParams np;
    for (int gy = 0; gy < 3; ++gy) {
        np.A[gy] = h_item; np.Bcol[gy] = B_item + gy * 128;
        np.biasc[gy] = bias_item + gy * 128; np.stride[gy] = 384;
    }
    for (int gy = 3; gy < 7; ++gy) {
        np.A[gy] = h_user; np.Bcol[gy] = B_user + (gy - 3) * 128;
        np.biasc[gy] = bias_user + (gy - 3) * 128; np.stride[gy] = 512;
    }
    np.out[0] = kb_i; np.out[1] = vb_i; np.out[2] = out_item;
    np.out[3] = kb_u; np.out[4] = vb_u; np.out[5] = out_user; np.out[6] = qt1;
    gemm_node<<<dim3(tiles, 7), 256, 0, stream>>>(np);

    // CSR build (fused over etypes)
    zero_int<<<(6 * NN + 255) / 256, 256, 0, stream>>>(ibuf, 6 * NN);  // cnt+pos
    hist3<<<(Etot + 255) / 256, 256, 0, stream>>>(d0, d1, d2, E0, E1, E2, cnt);
    const int nscan = 3 * NN;
    const int nb1024 = (nscan + 1023) / 1024;  // 293
    scan1<<<nb1024, 1024, 0, stream>>>(cnt, offs, psum, nscan);
    scan2<<<1, 512, 0, stream>>>(psum, nb1024);
    scan3<<<(nscan + 255) / 256, 256, 0, stream>>>(offs, psum, nscan);
    scatter3<<<(Etot + 255) / 256, 256, 0, stream>>>(s0, d0, s1, d1, s2, d2,
                                                     E0, E1, E2, offs, pos, csrc);

    // attention + aggregation, all 3 etypes in one dispatch (agg aliases qt)
    EdgeParams ep;
    ep.qt[0] = out_user; ep.kb[0] = kb_i; ep.vb[0] = vb_i; ep.agg[0] = out_user;
    ep.qt[1] = qt1;      ep.kb[1] = kb_i; ep.vb[1] = vb_i; ep.agg[1] = qt1;
    ep.qt[2] = out_item; ep.kb[2] = kb_u; ep.vb[2] = vb_u; ep.agg[2] = out_item;
    edge_attn<<<dim3((NN + 31) / 32, 3), 256, 0, stream>>>(ep, offs, cnt, csrc);

    FinParams fp;
    fp.A0[0] = out_item; fp.A1[0] = nullptr;
    fp.B0[0] = Wfin;     fp.B1[0] = nullptr;
    fp.ba[0] = ba;       fp.hin[0] = h_item; fp.out[0] = out_item;
    fp.A0[1] = out_user; fp.A1[1] = qt1;
    fp.B0[1] = Wfin + 16384; fp.B1[1] = Wfin + 2 * 16384;
    fp.ba[1] = ba + 128; fp.hin[1] = h_user; fp.out[1] = out_user;
    gemm_final<<<dim3(tiles, 2), 256, 0, stream>>>(fp, skipv);
}